// Round 1
// baseline (533.949 us; speedup 1.0000x reference)
//
#include <hip/hip_runtime.h>

#define DEV __device__ __forceinline__

typedef _Float16 f16x8 __attribute__((ext_vector_type(8)));
typedef float f32x4 __attribute__((ext_vector_type(4)));
typedef unsigned int u32x4 __attribute__((ext_vector_type(4)));

// Closed-form uniform cubic B-spline (knots (j-3)*0.4-1), verified vs Cox-de Boor (R9).
// All KAN-layer inputs are >= 0, so B_0,B_1 == 0. Record: [silu, B_2..B_7, 0].
DEV f16x8 kan_feats8(float x) {
    const float sil = x / (1.0f + __expf(-x));
    const float k0 = (float)(-3) * 0.4f - 1.0f;
    const float t = (x - k0) * 2.5f;
    const float mf = floorf(t);
    const int m = (int)mf;
    const float u = t - mf, v = 1.0f - u;
    const float u2 = u * u, u3 = u2 * u;
    const float N0 = v * v * v * (1.0f / 6.0f);
    const float N1 = (3.0f * u3 - 6.0f * u2 + 4.0f) * (1.0f / 6.0f);
    const float N2 = (-3.0f * u3 + 3.0f * u2 + 3.0f * u + 1.0f) * (1.0f / 6.0f);
    const float N3 = u3 * (1.0f / 6.0f);
    f16x8 g;
    g[0] = (_Float16)sil;
#pragma unroll
    for (int jj = 0; jj < 6; ++jj) {
        const int j = jj + 2;
        float val = 0.0f;
        val = (m == j + 3) ? N0 : val;
        val = (m == j + 2) ? N1 : val;
        val = (m == j + 1) ? N2 : val;
        val = (m == j)     ? N3 : val;
        g[1 + jj] = (_Float16)val;
    }
    g[7] = (_Float16)0.0f;
    return g;
}

// Full 9-feature version (head path).
DEV void kan_feats9(float x, float* f) {
    f[0] = x / (1.0f + __expf(-x));
    const float k0 = (float)(-3) * 0.4f - 1.0f;
    const float t = (x - k0) * 2.5f;
    const float mf = floorf(t);
    const int m = (int)mf;
    const float u = t - mf, v = 1.0f - u;
    const float u2 = u * u, u3 = u2 * u;
    const float N0 = v * v * v * (1.0f / 6.0f);
    const float N1 = (3.0f * u3 - 6.0f * u2 + 4.0f) * (1.0f / 6.0f);
    const float N2 = (-3.0f * u3 + 3.0f * u2 + 3.0f * u + 1.0f) * (1.0f / 6.0f);
    const float N3 = u3 * (1.0f / 6.0f);
#pragma unroll
    for (int j = 0; j < 8; ++j) {
        float val = 0.0f;
        val = (m == j + 3) ? N0 : val;
        val = (m == j + 2) ? N1 : val;
        val = (m == j + 1) ? N2 : val;
        val = (m == j)     ? N3 : val;
        f[1 + j] = val;
    }
}

// LDS A-plane byte offsets (pitch-8 records: one 16B octet per input).
__device__ constexpr int d_l0(int ii) {   // L0: (ci,kh,kw) over 3x7x7
    const int i = ii > 146 ? 146 : ii;    // i=147 zero-weight pad slot
    const int ci = i / 49, rem = i % 49, kh = rem / 7, kw = rem % 7;
    return ((((kw & 1) * 3 + ci) * 13 + kh) * 19 + (kw >> 1)) * 16;
}
__device__ constexpr int d_l1(int i) {    // L1: (ch,kh,kw) over 16x3x3
    const int ch = i / 9, rem = i % 9, kh = rem / 3, kw = rem % 3;
    return ((((kw & 1) * 16 + ch) * 9 + kh) * 5 + (kw >> 1)) * 16;
}

// Reduced weight octet: t=0 base, t=1..6 -> sw[j=t+1]*sc, t=7 = 0.
template <int OUT_F, int IN_F>
DEV void pack_oct8(int g, const float* bw, const float* sw, const float* sc,
                   _Float16* W2) {
    const int o = g % OUT_F, i = g / OUT_F;
    f16x8 v;
    if (i < IN_F) {
        const int wi = o * IN_F + i;
        const float s = sc[wi];
        v[0] = (_Float16)bw[wi];
#pragma unroll
        for (int t = 1; t <= 6; ++t) v[t] = (_Float16)(sw[wi * 8 + t + 1] * s);
        v[7] = (_Float16)0.0f;
    } else {
#pragma unroll
        for (int t = 0; t < 8; ++t) v[t] = (_Float16)0.0f;
    }
    *(f16x8*)(W2 + g * 8) = v;
}

#define PS0 2368   // L0: 148 koct * 16
#define PS1 4608   // L1: 144 koct * 32
#define PS2 18432  // L2: 288 koct * 64
#define PS3 12800  // head
#define PS4 25088  // h2 zero
#define PSUM (PS0 + PS1 + PS2 + PS3 + PS4)

#define NBLK 784   // co-resident: LDS 27136B -> >=5 blk/CU; VGPR<=128 -> >=4 blk/CU; cap>=1024

// Manual grid barrier (capacity-guaranteed residency). Per-phase counter+flag,
// 256B apart. Arrivals: fence + atomicAdd. Block 0 is the sole counter poller
// (avoids 784-way RMW storm); others poll the release flag (cheap agent loads).
DEV void gbar(unsigned int* bars, int k) {
    __syncthreads();
    if (threadIdx.x == 0) {
        unsigned int* cnt = bars + k * 64;
        unsigned int* flg = cnt + 32;
        __threadfence();                       // release our phase's writes (agent scope)
        atomicAdd(cnt, 1u);
        if (blockIdx.x == 0) {
            while (atomicAdd(cnt, 0u) < (unsigned int)NBLK) __builtin_amdgcn_s_sleep(1);
            __hip_atomic_store(flg, 1u, __ATOMIC_RELEASE, __HIP_MEMORY_SCOPE_AGENT);
        } else {
            while (__hip_atomic_load(flg, __ATOMIC_ACQUIRE, __HIP_MEMORY_SCOPE_AGENT) == 0u)
                __builtin_amdgcn_s_sleep(4);
        }
        __threadfence();                       // acquire: see producers' writes
    }
    __syncthreads();
}

// Whole network in one launch: prep | conv0 (2 tiles/blk) | conv1 | conv2 (9-way K)
// | head (32 blk), separated by 4 grid barriers. LDS union = 27136 B.
__global__ __launch_bounds__(256, 4) void fused_k(
    const float* __restrict__ x,
    const float* __restrict__ bw0, const float* __restrict__ sw0, const float* __restrict__ sc0,
    const float* __restrict__ bw1, const float* __restrict__ sw1, const float* __restrict__ sc1,
    const float* __restrict__ bw2, const float* __restrict__ sw2, const float* __restrict__ sc2,
    const float* __restrict__ bwc, const float* __restrict__ swc, const float* __restrict__ scc,
    _Float16* __restrict__ W2_0, _Float16* __restrict__ W2_1, _Float16* __restrict__ W2_2,
    float* __restrict__ wcT, float* __restrict__ h2,
    float* __restrict__ p0, unsigned int* __restrict__ featP1,
    float* __restrict__ out, unsigned int* __restrict__ bars) {
    __shared__ __align__(16) char smem[27136];
    const int tid = threadIdx.x;
    const int bb = blockIdx.x;

    // ---------------- phase P: weight prep + h2 zero ----------------
    {
        const int e = bb * 256 + tid;
        if (e < PS0) {
            pack_oct8<16, 147>(e, bw0, sw0, sc0, W2_0);
        } else if (e < PS0 + PS1) {
            pack_oct8<32, 144>(e - PS0, bw1, sw1, sc1, W2_1);
        } else if (e < PS0 + PS1 + PS2) {
            pack_oct8<64, 288>(e - PS0 - PS1, bw2, sw2, sc2, W2_2);
        } else if (e < PS0 + PS1 + PS2 + PS3) {
            const int ee = e - PS0 - PS1 - PS2;
            const int o = ee / 64, i = ee - o * 64;
            const float s = scc[ee];
            wcT[(i * 9 + 0) * 200 + o] = bwc[ee];
#pragma unroll
            for (int t = 0; t < 8; ++t)
                wcT[(i * 9 + 1 + t) * 200 + o] = swc[ee * 8 + t] * s;
        } else if (e < PSUM) {
            h2[e - PS0 - PS1 - PS2 - PS3] = 0.0f;
        }
    }
    gbar(bars, 0);

    // ---------------- phase 0: conv0, 2 tiles per block ----------------
    {
        _Float16* feats = (_Float16*)smem;          // 1482*8 f16 = 23712 B
        float* pb = (float*)(smem + 23712);         // 4*8*16 f32 = 2048 B
        for (int rep = 0; rep < 2; ++rep) {
            const int vt = bb + rep * NBLK;         // 0..1567, exactly even split
            const int b = vt / 196;
            const int r0 = vt - b * 196;
            const int bh = r0 / 7, bw = r0 - (r0 / 7) * 7;
            const int ih0 = bh * 8 - 3, iw0 = bw * 32 - 3;
            for (int t = tid; t < 1482; t += 256) {
                const int iwh = t % 19;
                int r = t / 19;
                const int ihp = r % 13; r /= 13;
                const int ci = r % 3;
                const int par = r / 3;
                const int ih = ih0 + ihp, iw = iw0 + 2 * iwh + par;
                float xv = 0.0f;
                if (ih >= 0 && ih < 224 && iw >= 0 && iw < 224)
                    xv = x[((b * 3 + ci) * 224 + ih) * 224 + iw];
                *(f16x8*)(feats + t * 8) = kan_feats8(xv);
            }
            __syncthreads();
            const int lane = tid & 63, mt = tid >> 6;
            const int l15 = lane & 15, q = lane >> 4;
            const bool q1 = q & 1, q2 = q & 2;
            const char* aBase = (const char*)feats + ((2 * mt) * 19 + l15) * 16;
            const f16x8* __restrict__ Wv = (const f16x8*)W2_0;
            f32x4 acc = {0.f, 0.f, 0.f, 0.f};
#pragma unroll
            for (int s = 0; s < 37; ++s) {
                const int o0 = d_l0(4 * s), o1 = d_l0(4 * s + 1);
                const int o2 = d_l0(4 * s + 2), o3 = d_l0(4 * s + 3);
                const int e01 = q1 ? o1 : o0;
                const int e23 = q1 ? o3 : o2;
                const int aoff = q2 ? e23 : e01;
                const f16x8 a = *(const f16x8*)(aBase + aoff);
                const f16x8 bf = Wv[(s * 4 + q) * 16 + l15];
                acc = __builtin_amdgcn_mfma_f32_16x16x32_f16(a, bf, acc, 0, 0, 0);
            }
            pb[(mt * 8 + 2 * q + 0) * 16 + l15] = fmaxf(fmaxf(acc[0], 0.f), fmaxf(acc[1], 0.f));
            pb[(mt * 8 + 2 * q + 1) * 16 + l15] = fmaxf(fmaxf(acc[2], 0.f), fmaxf(acc[3], 0.f));
            __syncthreads();
            const int pr = tid >> 7, o = (tid >> 3) & 15, wp = tid & 7;
            const float v = fmaxf(pb[((2 * pr) * 8 + wp) * 16 + o],
                                  pb[((2 * pr + 1) * 8 + wp) * 16 + o]);
            p0[((b * 16 + o) * 56 + bh * 2 + pr) * 56 + bw * 8 + wp] = v;
            __syncthreads();   // protect feats/pb reuse across reps
        }
    }
    gbar(bars, 1);

    // ---------------- phase 1: conv1 (blocks 0..391) ----------------
    if (bb < 392) {
        _Float16* feats = (_Float16*)smem;          // 1440*8 f16 = 23040 B
        float* abuf = (float*)(smem + 23040);       // 2*32*16 f32 = 4096 B
        const int b = bb / 49;
        const int r0 = bb - b * 49;
        const int bh = r0 / 7, bw = r0 - (r0 / 7) * 7;
        const int ih0 = bh * 8 - 1, iw0 = bw * 8 - 1;
        for (int t = tid; t < 1296; t += 256) {
            const int iwp = t % 9;
            int r = t / 9;
            const int ihp = r % 9;
            const int ch = r / 9;
            const int ih = ih0 + ihp, iw = iw0 + iwp;
            float xv = 0.0f;
            if (ih >= 0 && ih < 56 && iw >= 0 && iw < 56)
                xv = p0[((b * 16 + ch) * 56 + ih) * 56 + iw];
            const int slot = (((iwp & 1) * 16 + ch) * 9 + ihp) * 5 + (iwp >> 1);
            *(f16x8*)(feats + slot * 8) = kan_feats8(xv);
        }
        __syncthreads();
        const int lane = tid & 63, w = tid >> 6;
        const int kc = w >> 1, ot = w & 1;
        const int l15 = lane & 15, q = lane >> 4;
        const bool q1 = q & 1, q2 = q & 2;
        const int mh = l15 >> 2, mw = l15 & 3;
        const int ocol = ot * 16 + l15;
        const char* aBase = (const char*)feats + ((2 * mh) * 5 + mw) * 16 + kc * 5760;
        const f16x8* __restrict__ Wv = (const f16x8*)W2_1;
        f32x4 acc = {0.f, 0.f, 0.f, 0.f};
#pragma unroll
        for (int s = 0; s < 18; ++s) {
            const int o0 = d_l1(4 * s), o1 = d_l1(4 * s + 1);
            const int o2 = d_l1(4 * s + 2), o3 = d_l1(4 * s + 3);
            const int e01 = q1 ? o1 : o0;
            const int e23 = q1 ? o3 : o2;
            const int aoff = q2 ? e23 : e01;
            const f16x8 a = *(const f16x8*)(aBase + aoff);
            const f16x8 bf = Wv[(kc * 72 + s * 4 + q) * 32 + ocol];
            acc = __builtin_amdgcn_mfma_f32_16x16x32_f16(a, bf, acc, 0, 0, 0);
        }
#pragma unroll
        for (int reg = 0; reg < 4; ++reg)
            abuf[(kc * 32 + ocol) * 16 + q * 4 + reg] = acc[reg];
        __syncthreads();
        if (tid < 128) {
            const int o = tid >> 2, pp = tid & 3;
            const int hp = pp >> 1, wp = pp & 1;
            float mx = -1e30f;
#pragma unroll
            for (int dh = 0; dh < 2; ++dh)
#pragma unroll
                for (int dw = 0; dw < 2; ++dw) {
                    const int m = (2 * hp + dh) * 4 + 2 * wp + dw;
                    const float s = abuf[(0 * 32 + o) * 16 + m] + abuf[(1 * 32 + o) * 16 + m];
                    mx = fmaxf(mx, fmaxf(s, 0.0f));
                }
            const f16x8 g = kan_feats8(mx);
            const size_t idx = ((b * 32 + o) * 14 + bh * 2 + hp) * 14 + bw * 2 + wp;
            *(u32x4*)(featP1 + idx * 4) = __builtin_bit_cast(u32x4, g);
        }
    }
    gbar(bars, 2);

    // ---------------- phase 2: conv2, 9-way K-split (blocks 0..224) ----------------
    if (bb < 225) {
        unsigned int* featW = (unsigned int*)smem;   // 16*132 u32 = 8448 B
        const int c = bb % 9, rt = bb / 9;
        const int lane = tid & 63, ot = tid >> 6;
        const int q = lane >> 4, l15 = lane & 15;
        const int ocol = ot * 16 + l15;
        const u32x4 F0p = __builtin_bit_cast(u32x4, kan_feats8(0.0f));
        const int i_in = tid & 31, rbase = tid >> 5;
        int hi0[2], wi0[2], pixb[2];
        bool rv[2];
#pragma unroll
        for (int t = 0; t < 2; ++t) {
            const int n = rt * 16 + rbase + t * 8;
            const int wo_ = n % 7, ho_ = (n / 7) % 7, b_ = n / 49;
            rv[t] = (n < 392);
            hi0[t] = ho_ * 2 - 1;
            wi0[t] = wo_ * 2 - 1;
            pixb[t] = b_ * 32 * 14 * 14;
        }
        f32x4 acc = {0.f, 0.f, 0.f, 0.f};
        const f16x8* __restrict__ Wv = (const f16x8*)W2_2;
        {
            const int ii = c * 32 + i_in;
            const int ci = ii / 9, rem = ii - ci * 9;
            const int kh = rem / 3, kw = rem - kh * 3;
#pragma unroll
            for (int t = 0; t < 2; ++t) {
                const int hi = hi0[t] + kh, wi = wi0[t] + kw;
                const bool v = rv[t] && hi >= 0 && hi < 14 && wi >= 0 && wi < 14;
                u32x4 rec = F0p;
                if (v)
                    rec = *(const u32x4*)(featP1 + (size_t)(pixb[t] + (ci * 14 + hi) * 14 + wi) * 4);
                *(u32x4*)(featW + (rbase + t * 8) * 132 + i_in * 4) = rec;
            }
            __syncthreads();
            const char* arow = (const char*)featW + l15 * 528 + q * 16;
#pragma unroll
            for (int s = 0; s < 8; ++s) {
                const f16x8 a = *(const f16x8*)(arow + s * 64);
                const f16x8 bf = Wv[(c * 32 + s * 4 + q) * 64 + ocol];
                acc = __builtin_amdgcn_mfma_f32_16x16x32_f16(a, bf, acc, 0, 0, 0);
            }
        }
#pragma unroll
        for (int reg = 0; reg < 4; ++reg) {
            const int n = rt * 16 + q * 4 + reg;
            if (n < 392) {
                const int wo_ = n % 7, ho_ = (n / 7) % 7, b_ = n / 49;
                atomicAdd(h2 + ((b_ * 64 + ocol) * 7 + ho_) * 7 + wo_, acc[reg]);
            }
        }
    }
    gbar(bars, 3);

    // ---------------- phase 3: head, 32 blocks (n x 4 o-chunks, 4-way K-split) ----
    if (bb < 32) {
        float* feat = (float*)smem;                  // 576 f32
        float* psum = (float*)(smem + 2304);         // 4*64 f32
        const int n = bb >> 2, oc = bb & 3;
        if (tid < 64) {
            const float* p = h2 + (n * 64 + tid) * 49;
            float s = 0.0f;
            for (int j = 0; j < 49; ++j) s += fmaxf(p[j], 0.0f);
            float f9[9];
            kan_feats9(s / 49.0f, f9);
#pragma unroll
            for (int t = 0; t < 9; ++t) feat[tid * 9 + t] = f9[t];
        }
        __syncthreads();
        const int js = tid >> 6, ol = tid & 63;
        if (ol < 50) {
            const int o = oc * 50 + ol;
            float sum = 0.0f;
            for (int j = js * 144; j < js * 144 + 144; ++j)
                sum += feat[j] * wcT[j * 200 + o];
            psum[js * 64 + ol] = sum;
        }
        __syncthreads();
        if (tid < 50)
            out[n * 200 + oc * 50 + tid] =
                psum[tid] + psum[64 + tid] + psum[128 + tid] + psum[192 + tid];
    }
}

extern "C" void kernel_launch(void* const* d_in, const int* in_sizes, int n_in,
                              void* d_out, int out_size, void* d_ws, size_t ws_size,
                              hipStream_t stream) {
    const float* x   = (const float*)d_in[0];
    const float* bw0 = (const float*)d_in[1];
    const float* sw0 = (const float*)d_in[2];
    const float* sc0 = (const float*)d_in[3];
    const float* bw1 = (const float*)d_in[4];
    const float* sw1 = (const float*)d_in[5];
    const float* sc1 = (const float*)d_in[6];
    const float* bw2 = (const float*)d_in[7];
    const float* sw2 = (const float*)d_in[8];
    const float* sc2 = (const float*)d_in[9];
    const float* bwc = (const float*)d_in[10];
    const float* swc = (const float*)d_in[11];
    const float* scc = (const float*)d_in[12];
    float* out = (float*)d_out;

    char* ws = (char*)d_ws;
    size_t off = 0;
    auto alloc = [&](size_t nbytes) {
        char* p = ws + off;
        off += (nbytes + 255) & ~(size_t)255;
        return p;
    };
    _Float16* W2_0 = (_Float16*)alloc(PS0 * 16);
    _Float16* W2_1 = (_Float16*)alloc(PS1 * 16);
    _Float16* W2_2 = (_Float16*)alloc(PS2 * 16);
    float* wcT = (float*)alloc(576 * 200 * 4);
    float* h2  = (float*)alloc(8 * 64 * 49 * 4);   // dedicated (atomic target)
    float* p0  = (float*)alloc((size_t)8 * 16 * 56 * 56 * 4);
    unsigned int* featP1 = (unsigned int*)alloc((size_t)8 * 32 * 14 * 14 * 16);
    unsigned int* bars = (unsigned int*)alloc(4 * 64 * sizeof(unsigned int));

    // Barrier counters/flags must be zero each replay (ws is poisoned between iters).
    hipMemsetAsync(bars, 0, 4 * 64 * sizeof(unsigned int), stream);
    fused_k<<<NBLK, 256, 0, stream>>>(
        x, bw0, sw0, sc0, bw1, sw1, sc1, bw2, sw2, sc2, bwc, swc, scc,
        W2_0, W2_1, W2_2, wcT, h2, p0, featP1, out, bars);
}

// Round 3
// 204.204 us; speedup vs baseline: 2.6148x; 2.6148x over previous
//
#include <hip/hip_runtime.h>

#define DEV __device__ __forceinline__

typedef _Float16 f16x8 __attribute__((ext_vector_type(8)));
typedef float f32x4 __attribute__((ext_vector_type(4)));
typedef unsigned int u32x4 __attribute__((ext_vector_type(4)));

// Closed-form uniform cubic B-spline (knots (j-3)*0.4-1), verified vs Cox-de Boor (R9).
// All KAN-layer inputs are >= 0, so B_0,B_1 == 0. Record: [silu, B_2..B_7, 0].
DEV f16x8 kan_feats8(float x) {
    const float sil = x / (1.0f + __expf(-x));
    const float k0 = (float)(-3) * 0.4f - 1.0f;
    const float t = (x - k0) * 2.5f;
    const float mf = floorf(t);
    const int m = (int)mf;
    const float u = t - mf, v = 1.0f - u;
    const float u2 = u * u, u3 = u2 * u;
    const float N0 = v * v * v * (1.0f / 6.0f);
    const float N1 = (3.0f * u3 - 6.0f * u2 + 4.0f) * (1.0f / 6.0f);
    const float N2 = (-3.0f * u3 + 3.0f * u2 + 3.0f * u + 1.0f) * (1.0f / 6.0f);
    const float N3 = u3 * (1.0f / 6.0f);
    f16x8 g;
    g[0] = (_Float16)sil;
#pragma unroll
    for (int jj = 0; jj < 6; ++jj) {
        const int j = jj + 2;
        float val = 0.0f;
        val = (m == j + 3) ? N0 : val;
        val = (m == j + 2) ? N1 : val;
        val = (m == j + 1) ? N2 : val;
        val = (m == j)     ? N3 : val;
        g[1 + jj] = (_Float16)val;
    }
    g[7] = (_Float16)0.0f;
    return g;
}

// Full 9-feature version (head path).
DEV void kan_feats9(float x, float* f) {
    f[0] = x / (1.0f + __expf(-x));
    const float k0 = (float)(-3) * 0.4f - 1.0f;
    const float t = (x - k0) * 2.5f;
    const float mf = floorf(t);
    const int m = (int)mf;
    const float u = t - mf, v = 1.0f - u;
    const float u2 = u * u, u3 = u2 * u;
    const float N0 = v * v * v * (1.0f / 6.0f);
    const float N1 = (3.0f * u3 - 6.0f * u2 + 4.0f) * (1.0f / 6.0f);
    const float N2 = (-3.0f * u3 + 3.0f * u2 + 3.0f * u + 1.0f) * (1.0f / 6.0f);
    const float N3 = u3 * (1.0f / 6.0f);
#pragma unroll
    for (int j = 0; j < 8; ++j) {
        float val = 0.0f;
        val = (m == j + 3) ? N0 : val;
        val = (m == j + 2) ? N1 : val;
        val = (m == j + 1) ? N2 : val;
        val = (m == j)     ? N3 : val;
        f[1 + j] = val;
    }
}

// LDS A-plane byte offsets (pitch-8 records: one 16B octet per input).
__device__ constexpr int d_l0(int ii) {   // L0: (ci,kh,kw) over 3x7x7
    const int i = ii > 146 ? 146 : ii;    // i=147 zero-weight pad slot
    const int ci = i / 49, rem = i % 49, kh = rem / 7, kw = rem % 7;
    return ((((kw & 1) * 3 + ci) * 13 + kh) * 19 + (kw >> 1)) * 16;
}
__device__ constexpr int d_l1(int i) {    // L1: (ch,kh,kw) over 16x3x3
    const int ch = i / 9, rem = i % 9, kh = rem / 3, kw = rem % 3;
    return ((((kw & 1) * 16 + ch) * 9 + kh) * 5 + (kw >> 1)) * 16;
}

// Reduced weight octet: t=0 base, t=1..6 -> sw[j=t+1]*sc, t=7 = 0.
template <int OUT_F, int IN_F>
DEV void pack_oct8(int g, const float* bw, const float* sw, const float* sc,
                   _Float16* W2) {
    const int o = g % OUT_F, i = g / OUT_F;
    f16x8 v;
    if (i < IN_F) {
        const int wi = o * IN_F + i;
        const float s = sc[wi];
        v[0] = (_Float16)bw[wi];
#pragma unroll
        for (int t = 1; t <= 6; ++t) v[t] = (_Float16)(sw[wi * 8 + t + 1] * s);
        v[7] = (_Float16)0.0f;
    } else {
#pragma unroll
        for (int t = 0; t < 8; ++t) v[t] = (_Float16)0.0f;
    }
    *(f16x8*)(W2 + g * 8) = v;
}

#define PS0 2368   // L0: 148 koct * 16
#define PS1 4608   // L1: 144 koct * 32
#define PS2 18432  // L2: 288 koct * 64
#define PS3 12800  // head
#define PS4 25088  // h2 zero
#define PSUM (PS0 + PS1 + PS2 + PS3 + PS4)

#define NBLK 784   // co-resident: LDS 27136B -> 6 blk/CU; VGPR<=128 -> >=4 blk/CU; cap >= 1024

// Manual grid barrier. Round-1 lesson: no ordering ops inside spin loops.
// Round-2 lesson: flag MUST NOT alias a sub-counter (was base+240 == counter 15).
// Layout per phase: 512 u32 (2KB). Arrival counters at j*16 (j=0..15, 64B apart,
// bytes 0..963). Release flag at index 496 (byte 1984, own cache line).
// Arrival: release fetch_add. Polls: RELAXED agent loads. One acquire fence at exit.
DEV void gbar(unsigned int* bars, int k) {
    __syncthreads();   // drains all waves' vmem (compiler emits vmcnt(0) before s_barrier)
    if (threadIdx.x == 0) {
        unsigned int* base = bars + k * 512;          // 2KB per phase
        unsigned int* flg = base + 496;               // own cache line, no counter alias
        __hip_atomic_fetch_add(base + (blockIdx.x & 15) * 16, 1u,
                               __ATOMIC_RELEASE, __HIP_MEMORY_SCOPE_AGENT);
        if (blockIdx.x == 0) {
            for (;;) {
                unsigned int s = 0;
#pragma unroll
                for (int j = 0; j < 16; ++j)
                    s += __hip_atomic_load(base + j * 16, __ATOMIC_RELAXED,
                                           __HIP_MEMORY_SCOPE_AGENT);
                if (s >= (unsigned int)NBLK) break;
                __builtin_amdgcn_s_sleep(8);
            }
            __builtin_amdgcn_fence(__ATOMIC_ACQUIRE, "agent");
            __hip_atomic_store(flg, 1u, __ATOMIC_RELEASE, __HIP_MEMORY_SCOPE_AGENT);
        } else {
            while (__hip_atomic_load(flg, __ATOMIC_RELAXED,
                                     __HIP_MEMORY_SCOPE_AGENT) == 0u)
                __builtin_amdgcn_s_sleep(2);
        }
        __builtin_amdgcn_fence(__ATOMIC_ACQUIRE, "agent");
    }
    __syncthreads();
}

// Whole network in one launch: prep | conv0 (2 tiles/blk, featurize-0 hoisted
// above barrier 0) | conv1 | conv2 (9-way K) | head, 4 grid barriers.
__global__ __launch_bounds__(256, 4) void fused_k(
    const float* __restrict__ x,
    const float* __restrict__ bw0, const float* __restrict__ sw0, const float* __restrict__ sc0,
    const float* __restrict__ bw1, const float* __restrict__ sw1, const float* __restrict__ sc1,
    const float* __restrict__ bw2, const float* __restrict__ sw2, const float* __restrict__ sc2,
    const float* __restrict__ bwc, const float* __restrict__ swc, const float* __restrict__ scc,
    _Float16* __restrict__ W2_0, _Float16* __restrict__ W2_1, _Float16* __restrict__ W2_2,
    float* __restrict__ wcT, float* __restrict__ h2,
    float* __restrict__ p0, unsigned int* __restrict__ featP1,
    float* __restrict__ out, unsigned int* __restrict__ bars) {
    __shared__ __align__(16) char smem[27136];
    const int tid = threadIdx.x;
    const int bb = blockIdx.x;

    // ---------------- phase P: weight prep + h2 zero (no LDS) ----------------
    {
        const int e = bb * 256 + tid;
        if (e < PS0) {
            pack_oct8<16, 147>(e, bw0, sw0, sc0, W2_0);
        } else if (e < PS0 + PS1) {
            pack_oct8<32, 144>(e - PS0, bw1, sw1, sc1, W2_1);
        } else if (e < PS0 + PS1 + PS2) {
            pack_oct8<64, 288>(e - PS0 - PS1, bw2, sw2, sc2, W2_2);
        } else if (e < PS0 + PS1 + PS2 + PS3) {
            const int ee = e - PS0 - PS1 - PS2;
            const int o = ee / 64, i = ee - o * 64;
            const float s = scc[ee];
            wcT[(i * 9 + 0) * 200 + o] = bwc[ee];
#pragma unroll
            for (int t = 0; t < 8; ++t)
                wcT[(i * 9 + 1 + t) * 200 + o] = swc[ee * 8 + t] * s;
        } else if (e < PSUM) {
            h2[e - PS0 - PS1 - PS2 - PS3] = 0.0f;
        }
    }

    // ---------------- phase 0: conv0, 2 tiles per block ----------------
    {
        _Float16* feats = (_Float16*)smem;          // 1482*8 f16 = 23712 B
        float* pb = (float*)(smem + 23712);         // 4*8*16 f32 = 2048 B

        auto featurize = [&](int vt) {
            const int b = vt / 196;
            const int r0 = vt - b * 196;
            const int bh = r0 / 7, bw_ = r0 - (r0 / 7) * 7;
            const int ih0 = bh * 8 - 3, iw0 = bw_ * 32 - 3;
            for (int t = tid; t < 1482; t += 256) {
                const int iwh = t % 19;
                int r = t / 19;
                const int ihp = r % 13; r /= 13;
                const int ci = r % 3;
                const int par = r / 3;
                const int ih = ih0 + ihp, iw = iw0 + 2 * iwh + par;
                float xv = 0.0f;
                if (ih >= 0 && ih < 224 && iw >= 0 && iw < 224)
                    xv = x[((b * 3 + ci) * 224 + ih) * 224 + iw];
                *(f16x8*)(feats + t * 8) = kan_feats8(xv);
            }
        };

        featurize(bb);            // tile 0, weight-independent: hide barrier 0 under it
        gbar(bars, 0);            // W2_* ready; also publishes feats within block

        const int lane = tid & 63, mt = tid >> 6;
        const int l15 = lane & 15, q = lane >> 4;
        const bool q1 = q & 1, q2 = q & 2;
        const char* aBase = (const char*)feats + ((2 * mt) * 19 + l15) * 16;
        const f16x8* __restrict__ Wv = (const f16x8*)W2_0;

#pragma unroll 1
        for (int rep = 0; rep < 2; ++rep) {
            const int vt = bb + rep * NBLK;         // 0..1567, even split
            f32x4 acc = {0.f, 0.f, 0.f, 0.f};
#pragma unroll
            for (int s = 0; s < 37; ++s) {
                const int o0 = d_l0(4 * s), o1 = d_l0(4 * s + 1);
                const int o2 = d_l0(4 * s + 2), o3 = d_l0(4 * s + 3);
                const int e01 = q1 ? o1 : o0;
                const int e23 = q1 ? o3 : o2;
                const int aoff = q2 ? e23 : e01;
                const f16x8 a = *(const f16x8*)(aBase + aoff);
                const f16x8 bf = Wv[(s * 4 + q) * 16 + l15];
                acc = __builtin_amdgcn_mfma_f32_16x16x32_f16(a, bf, acc, 0, 0, 0);
            }
            pb[(mt * 8 + 2 * q + 0) * 16 + l15] = fmaxf(fmaxf(acc[0], 0.f), fmaxf(acc[1], 0.f));
            pb[(mt * 8 + 2 * q + 1) * 16 + l15] = fmaxf(fmaxf(acc[2], 0.f), fmaxf(acc[3], 0.f));
            __syncthreads();
            // pool+store tile vt; concurrently featurize next tile (disjoint LDS)
            if (rep == 0) featurize(bb + NBLK);
            {
                const int b = vt / 196;
                const int r0 = vt - b * 196;
                const int bh = r0 / 7, bw_ = r0 - (r0 / 7) * 7;
                const int pr = tid >> 7, o = (tid >> 3) & 15, wp = tid & 7;
                const float v = fmaxf(pb[((2 * pr) * 8 + wp) * 16 + o],
                                      pb[((2 * pr + 1) * 8 + wp) * 16 + o]);
                p0[((b * 16 + o) * 56 + bh * 2 + pr) * 56 + bw_ * 8 + wp] = v;
            }
            __syncthreads();
        }
    }
    gbar(bars, 1);

    // ---------------- phase 1: conv1 (blocks 0..391) ----------------
    if (bb < 392) {
        _Float16* feats = (_Float16*)smem;          // 1440*8 f16 = 23040 B
        float* abuf = (float*)(smem + 23040);       // 2*32*16 f32 = 4096 B
        const int b = bb / 49;
        const int r0 = bb - b * 49;
        const int bh = r0 / 7, bw = r0 - (r0 / 7) * 7;
        const int ih0 = bh * 8 - 1, iw0 = bw * 8 - 1;
        for (int t = tid; t < 1296; t += 256) {
            const int iwp = t % 9;
            int r = t / 9;
            const int ihp = r % 9;
            const int ch = r / 9;
            const int ih = ih0 + ihp, iw = iw0 + iwp;
            float xv = 0.0f;
            if (ih >= 0 && ih < 56 && iw >= 0 && iw < 56)
                xv = p0[((b * 16 + ch) * 56 + ih) * 56 + iw];
            const int slot = (((iwp & 1) * 16 + ch) * 9 + ihp) * 5 + (iwp >> 1);
            *(f16x8*)(feats + slot * 8) = kan_feats8(xv);
        }
        __syncthreads();
        const int lane = tid & 63, w = tid >> 6;
        const int kc = w >> 1, ot = w & 1;
        const int l15 = lane & 15, q = lane >> 4;
        const bool q1 = q & 1, q2 = q & 2;
        const int mh = l15 >> 2, mw = l15 & 3;
        const int ocol = ot * 16 + l15;
        const char* aBase = (const char*)feats + ((2 * mh) * 5 + mw) * 16 + kc * 5760;
        const f16x8* __restrict__ Wv = (const f16x8*)W2_1;
        f32x4 acc = {0.f, 0.f, 0.f, 0.f};
#pragma unroll
        for (int s = 0; s < 18; ++s) {
            const int o0 = d_l1(4 * s), o1 = d_l1(4 * s + 1);
            const int o2 = d_l1(4 * s + 2), o3 = d_l1(4 * s + 3);
            const int e01 = q1 ? o1 : o0;
            const int e23 = q1 ? o3 : o2;
            const int aoff = q2 ? e23 : e01;
            const f16x8 a = *(const f16x8*)(aBase + aoff);
            const f16x8 bf = Wv[(kc * 72 + s * 4 + q) * 32 + ocol];
            acc = __builtin_amdgcn_mfma_f32_16x16x32_f16(a, bf, acc, 0, 0, 0);
        }
#pragma unroll
        for (int reg = 0; reg < 4; ++reg)
            abuf[(kc * 32 + ocol) * 16 + q * 4 + reg] = acc[reg];
        __syncthreads();
        if (tid < 128) {
            const int o = tid >> 2, pp = tid & 3;
            const int hp = pp >> 1, wp = pp & 1;
            float mx = -1e30f;
#pragma unroll
            for (int dh = 0; dh < 2; ++dh)
#pragma unroll
                for (int dw = 0; dw < 2; ++dw) {
                    const int m = (2 * hp + dh) * 4 + 2 * wp + dw;
                    const float s = abuf[(0 * 32 + o) * 16 + m] + abuf[(1 * 32 + o) * 16 + m];
                    mx = fmaxf(mx, fmaxf(s, 0.0f));
                }
            const f16x8 g = kan_feats8(mx);
            const size_t idx = ((b * 32 + o) * 14 + bh * 2 + hp) * 14 + bw * 2 + wp;
            *(u32x4*)(featP1 + idx * 4) = __builtin_bit_cast(u32x4, g);
        }
    }
    gbar(bars, 2);

    // ---------------- phase 2: conv2, 9-way K-split (blocks 0..224) ----------------
    if (bb < 225) {
        unsigned int* featW = (unsigned int*)smem;   // 16*132 u32 = 8448 B
        const int c = bb % 9, rt = bb / 9;
        const int lane = tid & 63, ot = tid >> 6;
        const int q = lane >> 4, l15 = lane & 15;
        const int ocol = ot * 16 + l15;
        const u32x4 F0p = __builtin_bit_cast(u32x4, kan_feats8(0.0f));
        const int i_in = tid & 31, rbase = tid >> 5;
        int hi0[2], wi0[2], pixb[2];
        bool rv[2];
#pragma unroll
        for (int t = 0; t < 2; ++t) {
            const int n = rt * 16 + rbase + t * 8;
            const int wo_ = n % 7, ho_ = (n / 7) % 7, b_ = n / 49;
            rv[t] = (n < 392);
            hi0[t] = ho_ * 2 - 1;
            wi0[t] = wo_ * 2 - 1;
            pixb[t] = b_ * 32 * 14 * 14;
        }
        f32x4 acc = {0.f, 0.f, 0.f, 0.f};
        const f16x8* __restrict__ Wv = (const f16x8*)W2_2;
        {
            const int ii = c * 32 + i_in;
            const int ci = ii / 9, rem = ii - ci * 9;
            const int kh = rem / 3, kw = rem - kh * 3;
#pragma unroll
            for (int t = 0; t < 2; ++t) {
                const int hi = hi0[t] + kh, wi = wi0[t] + kw;
                const bool v = rv[t] && hi >= 0 && hi < 14 && wi >= 0 && wi < 14;
                u32x4 rec = F0p;
                if (v)
                    rec = *(const u32x4*)(featP1 + (size_t)(pixb[t] + (ci * 14 + hi) * 14 + wi) * 4);
                *(u32x4*)(featW + (rbase + t * 8) * 132 + i_in * 4) = rec;
            }
            __syncthreads();
            const char* arow = (const char*)featW + l15 * 528 + q * 16;
#pragma unroll
            for (int s = 0; s < 8; ++s) {
                const f16x8 a = *(const f16x8*)(arow + s * 64);
                const f16x8 bf = Wv[(c * 32 + s * 4 + q) * 64 + ocol];
                acc = __builtin_amdgcn_mfma_f32_16x16x32_f16(a, bf, acc, 0, 0, 0);
            }
        }
#pragma unroll
        for (int reg = 0; reg < 4; ++reg) {
            const int n = rt * 16 + q * 4 + reg;
            if (n < 392) {
                const int wo_ = n % 7, ho_ = (n / 7) % 7, b_ = n / 49;
                atomicAdd(h2 + ((b_ * 64 + ocol) * 7 + ho_) * 7 + wo_, acc[reg]);
            }
        }
    }
    gbar(bars, 3);

    // ---------------- phase 3: head, 32 blocks (n x 4 o-chunks, 4-way K-split) ----
    if (bb < 32) {
        float* feat = (float*)smem;                  // 576 f32
        float* psum = (float*)(smem + 2304);         // 4*64 f32
        const int n = bb >> 2, oc = bb & 3;
        if (tid < 64) {
            const float* p = h2 + (n * 64 + tid) * 49;
            float s = 0.0f;
            for (int j = 0; j < 49; ++j) s += fmaxf(p[j], 0.0f);
            float f9[9];
            kan_feats9(s / 49.0f, f9);
#pragma unroll
            for (int t = 0; t < 9; ++t) feat[tid * 9 + t] = f9[t];
        }
        __syncthreads();
        const int js = tid >> 6, ol = tid & 63;
        if (ol < 50) {
            const int o = oc * 50 + ol;
            float sum = 0.0f;
            for (int j = js * 144; j < js * 144 + 144; ++j)
                sum += feat[j] * wcT[j * 200 + o];
            psum[js * 64 + ol] = sum;
        }
        __syncthreads();
        if (tid < 50)
            out[n * 200 + oc * 50 + tid] =
                psum[tid] + psum[64 + tid] + psum[128 + tid] + psum[192 + tid];
    }
}

extern "C" void kernel_launch(void* const* d_in, const int* in_sizes, int n_in,
                              void* d_out, int out_size, void* d_ws, size_t ws_size,
                              hipStream_t stream) {
    const float* x   = (const float*)d_in[0];
    const float* bw0 = (const float*)d_in[1];
    const float* sw0 = (const float*)d_in[2];
    const float* sc0 = (const float*)d_in[3];
    const float* bw1 = (const float*)d_in[4];
    const float* sw1 = (const float*)d_in[5];
    const float* sc1 = (const float*)d_in[6];
    const float* bw2 = (const float*)d_in[7];
    const float* sw2 = (const float*)d_in[8];
    const float* sc2 = (const float*)d_in[9];
    const float* bwc = (const float*)d_in[10];
    const float* swc = (const float*)d_in[11];
    const float* scc = (const float*)d_in[12];
    float* out = (float*)d_out;

    char* ws = (char*)d_ws;
    size_t off = 0;
    auto alloc = [&](size_t nbytes) {
        char* p = ws + off;
        off += (nbytes + 255) & ~(size_t)255;
        return p;
    };
    _Float16* W2_0 = (_Float16*)alloc(PS0 * 16);
    _Float16* W2_1 = (_Float16*)alloc(PS1 * 16);
    _Float16* W2_2 = (_Float16*)alloc(PS2 * 16);
    float* wcT = (float*)alloc(576 * 200 * 4);
    float* h2  = (float*)alloc(8 * 64 * 49 * 4);   // dedicated (atomic target)
    float* p0  = (float*)alloc((size_t)8 * 16 * 56 * 56 * 4);
    unsigned int* featP1 = (unsigned int*)alloc((size_t)8 * 32 * 14 * 14 * 16);
    unsigned int* bars = (unsigned int*)alloc(4 * 512 * sizeof(unsigned int));

    // Barrier counters/flags must be zero each replay (ws is poisoned between iters).
    hipMemsetAsync(bars, 0, 4 * 512 * sizeof(unsigned int), stream);
    fused_k<<<NBLK, 256, 0, stream>>>(
        x, bw0, sw0, sc0, bw1, sw1, sc1, bw2, sw2, sc2, bwc, swc, scc,
        W2_0, W2_1, W2_2, wcT, h2, p0, featP1, out, bars);
}

// Round 4
// 142.956 us; speedup vs baseline: 3.7351x; 1.4284x over previous
//
#include <hip/hip_runtime.h>

#define DEV __device__ __forceinline__

typedef _Float16 f16x8 __attribute__((ext_vector_type(8)));
typedef float f32x4 __attribute__((ext_vector_type(4)));
typedef unsigned int u32x4 __attribute__((ext_vector_type(4)));

// Write-through stores to the coherence point (sc0 sc1): makes inter-phase data
// agent-visible per-instruction, so grid barriers need NO wbl2/inv cache fences
// (round-3 lesson: per-block release/acquire fences = full L2 writeback+inv, ~20us/barrier).
DEV void st16_wt(void* p, u32x4 v) {
    asm volatile("global_store_dwordx4 %0, %1, off sc0 sc1" :: "v"(p), "v"(v) : "memory");
}
DEV void st4_wt(float* p, float v) {
    asm volatile("global_store_dword %0, %1, off sc0 sc1" :: "v"(p), "v"(v) : "memory");
}

// Closed-form uniform cubic B-spline (knots (j-3)*0.4-1), verified vs Cox-de Boor (R9).
// All KAN-layer inputs are >= 0, so B_0,B_1 == 0. Record: [silu, B_2..B_7, 0].
DEV f16x8 kan_feats8(float x) {
    const float sil = x / (1.0f + __expf(-x));
    const float k0 = (float)(-3) * 0.4f - 1.0f;
    const float t = (x - k0) * 2.5f;
    const float mf = floorf(t);
    const int m = (int)mf;
    const float u = t - mf, v = 1.0f - u;
    const float u2 = u * u, u3 = u2 * u;
    const float N0 = v * v * v * (1.0f / 6.0f);
    const float N1 = (3.0f * u3 - 6.0f * u2 + 4.0f) * (1.0f / 6.0f);
    const float N2 = (-3.0f * u3 + 3.0f * u2 + 3.0f * u + 1.0f) * (1.0f / 6.0f);
    const float N3 = u3 * (1.0f / 6.0f);
    f16x8 g;
    g[0] = (_Float16)sil;
#pragma unroll
    for (int jj = 0; jj < 6; ++jj) {
        const int j = jj + 2;
        float val = 0.0f;
        val = (m == j + 3) ? N0 : val;
        val = (m == j + 2) ? N1 : val;
        val = (m == j + 1) ? N2 : val;
        val = (m == j)     ? N3 : val;
        g[1 + jj] = (_Float16)val;
    }
    g[7] = (_Float16)0.0f;
    return g;
}

// Full 9-feature version (head path).
DEV void kan_feats9(float x, float* f) {
    f[0] = x / (1.0f + __expf(-x));
    const float k0 = (float)(-3) * 0.4f - 1.0f;
    const float t = (x - k0) * 2.5f;
    const float mf = floorf(t);
    const int m = (int)mf;
    const float u = t - mf, v = 1.0f - u;
    const float u2 = u * u, u3 = u2 * u;
    const float N0 = v * v * v * (1.0f / 6.0f);
    const float N1 = (3.0f * u3 - 6.0f * u2 + 4.0f) * (1.0f / 6.0f);
    const float N2 = (-3.0f * u3 + 3.0f * u2 + 3.0f * u + 1.0f) * (1.0f / 6.0f);
    const float N3 = u3 * (1.0f / 6.0f);
#pragma unroll
    for (int j = 0; j < 8; ++j) {
        float val = 0.0f;
        val = (m == j + 3) ? N0 : val;
        val = (m == j + 2) ? N1 : val;
        val = (m == j + 1) ? N2 : val;
        val = (m == j)     ? N3 : val;
        f[1 + j] = val;
    }
}

// LDS A-plane byte offsets (pitch-8 records: one 16B octet per input).
__device__ constexpr int d_l0(int ii) {   // L0: (ci,kh,kw) over 3x7x7
    const int i = ii > 146 ? 146 : ii;    // i=147 zero-weight pad slot
    const int ci = i / 49, rem = i % 49, kh = rem / 7, kw = rem % 7;
    return ((((kw & 1) * 3 + ci) * 13 + kh) * 19 + (kw >> 1)) * 16;
}
__device__ constexpr int d_l1(int i) {    // L1: (ch,kh,kw) over 16x3x3
    const int ch = i / 9, rem = i % 9, kh = rem / 3, kw = rem % 3;
    return ((((kw & 1) * 16 + ch) * 9 + kh) * 5 + (kw >> 1)) * 16;
}

// Reduced weight octet: t=0 base, t=1..6 -> sw[j=t+1]*sc, t=7 = 0. sc1 write-through.
template <int OUT_F, int IN_F>
DEV void pack_oct8(int g, const float* bw, const float* sw, const float* sc,
                   _Float16* W2) {
    const int o = g % OUT_F, i = g / OUT_F;
    f16x8 v;
    if (i < IN_F) {
        const int wi = o * IN_F + i;
        const float s = sc[wi];
        v[0] = (_Float16)bw[wi];
#pragma unroll
        for (int t = 1; t <= 6; ++t) v[t] = (_Float16)(sw[wi * 8 + t + 1] * s);
        v[7] = (_Float16)0.0f;
    } else {
#pragma unroll
        for (int t = 0; t < 8; ++t) v[t] = (_Float16)0.0f;
    }
    st16_wt(W2 + g * 8, __builtin_bit_cast(u32x4, v));
}

#define PS0 2368   // L0: 148 koct * 16
#define PS1 4608   // L1: 144 koct * 32
#define PS2 18432  // L2: 288 koct * 64
#define PS3 12800  // head
#define PS4 25088  // h2 zero
#define PSUM (PS0 + PS1 + PS2 + PS3 + PS4)

#define NBLK 784   // co-resident: LDS 27136B -> 6 blk/CU; VGPR<=128 -> >=4 blk/CU; cap >= 1024

// Manual grid barrier, fence-free (all inter-phase data is sc1 write-through):
//  - explicit vmcnt(0) drains our inline-asm stores (compiler doesn't track them)
//  - arrival: RELAXED agent fetch_add over 16 sub-counters (64B apart)
//  - block 0 sums counters (relaxed), sets release flag (relaxed)
//  - waiters poll flag with RELAXED agent loads (no cache maintenance)
// Layout per phase: 512 u32 (2KB); counters at j*16 (j=0..15), flag at idx 496.
DEV void gbar(unsigned int* bars, int k) {
    asm volatile("s_waitcnt vmcnt(0)" ::: "memory");
    __syncthreads();
    if (threadIdx.x == 0) {
        unsigned int* base = bars + k * 512;
        unsigned int* flg = base + 496;
        __hip_atomic_fetch_add(base + (blockIdx.x & 15) * 16, 1u,
                               __ATOMIC_RELAXED, __HIP_MEMORY_SCOPE_AGENT);
        if (blockIdx.x == 0) {
            for (;;) {
                unsigned int s = 0;
#pragma unroll
                for (int j = 0; j < 16; ++j)
                    s += __hip_atomic_load(base + j * 16, __ATOMIC_RELAXED,
                                           __HIP_MEMORY_SCOPE_AGENT);
                if (s >= (unsigned int)NBLK) break;
                __builtin_amdgcn_s_sleep(8);
            }
            __hip_atomic_store(flg, 1u, __ATOMIC_RELAXED, __HIP_MEMORY_SCOPE_AGENT);
        } else {
            while (__hip_atomic_load(flg, __ATOMIC_RELAXED,
                                     __HIP_MEMORY_SCOPE_AGENT) == 0u)
                __builtin_amdgcn_s_sleep(2);
        }
        asm volatile("" ::: "memory");
    }
    __syncthreads();
}

// Whole network in one launch: prep | conv0 (2 tiles/blk, featurize-0 hoisted
// above barrier 0) | conv1 | conv2 (9-way K) | head, 4 grid barriers.
__global__ __launch_bounds__(256, 4) void fused_k(
    const float* __restrict__ x,
    const float* __restrict__ bw0, const float* __restrict__ sw0, const float* __restrict__ sc0,
    const float* __restrict__ bw1, const float* __restrict__ sw1, const float* __restrict__ sc1,
    const float* __restrict__ bw2, const float* __restrict__ sw2, const float* __restrict__ sc2,
    const float* __restrict__ bwc, const float* __restrict__ swc, const float* __restrict__ scc,
    _Float16* __restrict__ W2_0, _Float16* __restrict__ W2_1, _Float16* __restrict__ W2_2,
    float* __restrict__ wcT, float* __restrict__ h2,
    float* __restrict__ p0, unsigned int* __restrict__ featP1,
    float* __restrict__ out, unsigned int* __restrict__ bars) {
    __shared__ __align__(16) char smem[27136];
    const int tid = threadIdx.x;
    const int bb = blockIdx.x;

    // ---------------- phase P: weight prep + h2 zero (no LDS) ----------------
    {
        const int e = bb * 256 + tid;
        if (e < PS0) {
            pack_oct8<16, 147>(e, bw0, sw0, sc0, W2_0);
        } else if (e < PS0 + PS1) {
            pack_oct8<32, 144>(e - PS0, bw1, sw1, sc1, W2_1);
        } else if (e < PS0 + PS1 + PS2) {
            pack_oct8<64, 288>(e - PS0 - PS1, bw2, sw2, sc2, W2_2);
        } else if (e < PS0 + PS1 + PS2 + PS3) {
            const int ee = e - PS0 - PS1 - PS2;
            const int o = ee / 64, i = ee - o * 64;
            const float s = scc[ee];
            st4_wt(&wcT[(i * 9 + 0) * 200 + o], bwc[ee]);
#pragma unroll
            for (int t = 0; t < 8; ++t)
                st4_wt(&wcT[(i * 9 + 1 + t) * 200 + o], swc[ee * 8 + t] * s);
        } else if (e < PSUM) {
            st4_wt(&h2[e - PS0 - PS1 - PS2 - PS3], 0.0f);
        }
    }

    // ---------------- phase 0: conv0, 2 tiles per block ----------------
    {
        _Float16* feats = (_Float16*)smem;          // 1482*8 f16 = 23712 B
        float* pb = (float*)(smem + 23712);         // 4*8*16 f32 = 2048 B

        auto featurize = [&](int vt) {
            const int b = vt / 196;
            const int r0 = vt - b * 196;
            const int bh = r0 / 7, bw_ = r0 - (r0 / 7) * 7;
            const int ih0 = bh * 8 - 3, iw0 = bw_ * 32 - 3;
            for (int t = tid; t < 1482; t += 256) {
                const int iwh = t % 19;
                int r = t / 19;
                const int ihp = r % 13; r /= 13;
                const int ci = r % 3;
                const int par = r / 3;
                const int ih = ih0 + ihp, iw = iw0 + 2 * iwh + par;
                float xv = 0.0f;
                if (ih >= 0 && ih < 224 && iw >= 0 && iw < 224)
                    xv = x[((b * 3 + ci) * 224 + ih) * 224 + iw];
                *(f16x8*)(feats + t * 8) = kan_feats8(xv);
            }
        };

        featurize(bb);            // tile 0, weight-independent: hide barrier 0 under it
        gbar(bars, 0);            // W2_* ready; also publishes feats within block

        const int lane = tid & 63, mt = tid >> 6;
        const int l15 = lane & 15, q = lane >> 4;
        const bool q1 = q & 1, q2 = q & 2;
        const char* aBase = (const char*)feats + ((2 * mt) * 19 + l15) * 16;
        const f16x8* __restrict__ Wv = (const f16x8*)W2_0;

#pragma unroll 1
        for (int rep = 0; rep < 2; ++rep) {
            const int vt = bb + rep * NBLK;         // 0..1567, even split
            f32x4 acc = {0.f, 0.f, 0.f, 0.f};
#pragma unroll
            for (int s = 0; s < 37; ++s) {
                const int o0 = d_l0(4 * s), o1 = d_l0(4 * s + 1);
                const int o2 = d_l0(4 * s + 2), o3 = d_l0(4 * s + 3);
                const int e01 = q1 ? o1 : o0;
                const int e23 = q1 ? o3 : o2;
                const int aoff = q2 ? e23 : e01;
                const f16x8 a = *(const f16x8*)(aBase + aoff);
                const f16x8 bf = Wv[(s * 4 + q) * 16 + l15];
                acc = __builtin_amdgcn_mfma_f32_16x16x32_f16(a, bf, acc, 0, 0, 0);
            }
            pb[(mt * 8 + 2 * q + 0) * 16 + l15] = fmaxf(fmaxf(acc[0], 0.f), fmaxf(acc[1], 0.f));
            pb[(mt * 8 + 2 * q + 1) * 16 + l15] = fmaxf(fmaxf(acc[2], 0.f), fmaxf(acc[3], 0.f));
            __syncthreads();
            // pool+store tile vt; concurrently featurize next tile (disjoint LDS)
            if (rep == 0) featurize(bb + NBLK);
            {
                const int b = vt / 196;
                const int r0 = vt - b * 196;
                const int bh = r0 / 7, bw_ = r0 - (r0 / 7) * 7;
                const int pr = tid >> 7, o = (tid >> 3) & 15, wp = tid & 7;
                const float v = fmaxf(pb[((2 * pr) * 8 + wp) * 16 + o],
                                      pb[((2 * pr + 1) * 8 + wp) * 16 + o]);
                st4_wt(&p0[((b * 16 + o) * 56 + bh * 2 + pr) * 56 + bw_ * 8 + wp], v);
            }
            __syncthreads();
        }
    }
    gbar(bars, 1);

    // ---------------- phase 1: conv1 (blocks 0..391) ----------------
    if (bb < 392) {
        _Float16* feats = (_Float16*)smem;          // 1440*8 f16 = 23040 B
        float* abuf = (float*)(smem + 23040);       // 2*32*16 f32 = 4096 B
        const int b = bb / 49;
        const int r0 = bb - b * 49;
        const int bh = r0 / 7, bw = r0 - (r0 / 7) * 7;
        const int ih0 = bh * 8 - 1, iw0 = bw * 8 - 1;
        for (int t = tid; t < 1296; t += 256) {
            const int iwp = t % 9;
            int r = t / 9;
            const int ihp = r % 9;
            const int ch = r / 9;
            const int ih = ih0 + ihp, iw = iw0 + iwp;
            float xv = 0.0f;
            if (ih >= 0 && ih < 56 && iw >= 0 && iw < 56)
                xv = p0[((b * 16 + ch) * 56 + ih) * 56 + iw];
            const int slot = (((iwp & 1) * 16 + ch) * 9 + ihp) * 5 + (iwp >> 1);
            *(f16x8*)(feats + slot * 8) = kan_feats8(xv);
        }
        __syncthreads();
        const int lane = tid & 63, w = tid >> 6;
        const int kc = w >> 1, ot = w & 1;
        const int l15 = lane & 15, q = lane >> 4;
        const bool q1 = q & 1, q2 = q & 2;
        const int mh = l15 >> 2, mw = l15 & 3;
        const int ocol = ot * 16 + l15;
        const char* aBase = (const char*)feats + ((2 * mh) * 5 + mw) * 16 + kc * 5760;
        const f16x8* __restrict__ Wv = (const f16x8*)W2_1;
        f32x4 acc = {0.f, 0.f, 0.f, 0.f};
#pragma unroll
        for (int s = 0; s < 18; ++s) {
            const int o0 = d_l1(4 * s), o1 = d_l1(4 * s + 1);
            const int o2 = d_l1(4 * s + 2), o3 = d_l1(4 * s + 3);
            const int e01 = q1 ? o1 : o0;
            const int e23 = q1 ? o3 : o2;
            const int aoff = q2 ? e23 : e01;
            const f16x8 a = *(const f16x8*)(aBase + aoff);
            const f16x8 bf = Wv[(kc * 72 + s * 4 + q) * 32 + ocol];
            acc = __builtin_amdgcn_mfma_f32_16x16x32_f16(a, bf, acc, 0, 0, 0);
        }
#pragma unroll
        for (int reg = 0; reg < 4; ++reg)
            abuf[(kc * 32 + ocol) * 16 + q * 4 + reg] = acc[reg];
        __syncthreads();
        if (tid < 128) {
            const int o = tid >> 2, pp = tid & 3;
            const int hp = pp >> 1, wp = pp & 1;
            float mx = -1e30f;
#pragma unroll
            for (int dh = 0; dh < 2; ++dh)
#pragma unroll
                for (int dw = 0; dw < 2; ++dw) {
                    const int m = (2 * hp + dh) * 4 + 2 * wp + dw;
                    const float s = abuf[(0 * 32 + o) * 16 + m] + abuf[(1 * 32 + o) * 16 + m];
                    mx = fmaxf(mx, fmaxf(s, 0.0f));
                }
            const f16x8 g = kan_feats8(mx);
            const size_t idx = ((b * 32 + o) * 14 + bh * 2 + hp) * 14 + bw * 2 + wp;
            st16_wt(featP1 + idx * 4, __builtin_bit_cast(u32x4, g));
        }
    }
    gbar(bars, 2);

    // ---------------- phase 2: conv2, 9-way K-split (blocks 0..224) ----------------
    if (bb < 225) {
        unsigned int* featW = (unsigned int*)smem;   // 16*132 u32 = 8448 B
        const int c = bb % 9, rt = bb / 9;
        const int lane = tid & 63, ot = tid >> 6;
        const int q = lane >> 4, l15 = lane & 15;
        const int ocol = ot * 16 + l15;
        const u32x4 F0p = __builtin_bit_cast(u32x4, kan_feats8(0.0f));
        const int i_in = tid & 31, rbase = tid >> 5;
        int hi0[2], wi0[2], pixb[2];
        bool rv[2];
#pragma unroll
        for (int t = 0; t < 2; ++t) {
            const int n = rt * 16 + rbase + t * 8;
            const int wo_ = n % 7, ho_ = (n / 7) % 7, b_ = n / 49;
            rv[t] = (n < 392);
            hi0[t] = ho_ * 2 - 1;
            wi0[t] = wo_ * 2 - 1;
            pixb[t] = b_ * 32 * 14 * 14;
        }
        f32x4 acc = {0.f, 0.f, 0.f, 0.f};
        const f16x8* __restrict__ Wv = (const f16x8*)W2_2;
        {
            const int ii = c * 32 + i_in;
            const int ci = ii / 9, rem = ii - ci * 9;
            const int kh = rem / 3, kw = rem - kh * 3;
#pragma unroll
            for (int t = 0; t < 2; ++t) {
                const int hi = hi0[t] + kh, wi = wi0[t] + kw;
                const bool v = rv[t] && hi >= 0 && hi < 14 && wi >= 0 && wi < 14;
                u32x4 rec = F0p;
                if (v)
                    rec = *(const u32x4*)(featP1 + (size_t)(pixb[t] + (ci * 14 + hi) * 14 + wi) * 4);
                *(u32x4*)(featW + (rbase + t * 8) * 132 + i_in * 4) = rec;
            }
            __syncthreads();
            const char* arow = (const char*)featW + l15 * 528 + q * 16;
#pragma unroll
            for (int s = 0; s < 8; ++s) {
                const f16x8 a = *(const f16x8*)(arow + s * 64);
                const f16x8 bf = Wv[(c * 32 + s * 4 + q) * 64 + ocol];
                acc = __builtin_amdgcn_mfma_f32_16x16x32_f16(a, bf, acc, 0, 0, 0);
            }
        }
#pragma unroll
        for (int reg = 0; reg < 4; ++reg) {
            const int n = rt * 16 + q * 4 + reg;
            if (n < 392) {
                const int wo_ = n % 7, ho_ = (n / 7) % 7, b_ = n / 49;
                atomicAdd(h2 + ((b_ * 64 + ocol) * 7 + ho_) * 7 + wo_, acc[reg]);
            }
        }
    }
    gbar(bars, 3);

    // ---------------- phase 3: head, 32 blocks (n x 4 o-chunks, 4-way K-split) ----
    if (bb < 32) {
        float* feat = (float*)smem;                  // 576 f32
        float* psum = (float*)(smem + 2304);         // 4*64 f32
        const int n = bb >> 2, oc = bb & 3;
        if (tid < 64) {
            const float* p = h2 + (n * 64 + tid) * 49;
            float s = 0.0f;
            for (int j = 0; j < 49; ++j) {
                // h2 truth lives at the coherence point (atomics); bypass any stale L2 copy
                const float hv = __hip_atomic_load(p + j, __ATOMIC_RELAXED,
                                                   __HIP_MEMORY_SCOPE_AGENT);
                s += fmaxf(hv, 0.0f);
            }
            float f9[9];
            kan_feats9(s / 49.0f, f9);
#pragma unroll
            for (int t = 0; t < 9; ++t) feat[tid * 9 + t] = f9[t];
        }
        __syncthreads();
        const int js = tid >> 6, ol = tid & 63;
        if (ol < 50) {
            const int o = oc * 50 + ol;
            float sum = 0.0f;
            for (int j = js * 144; j < js * 144 + 144; ++j)
                sum += feat[j] * wcT[j * 200 + o];
            psum[js * 64 + ol] = sum;
        }
        __syncthreads();
        if (tid < 50)
            out[n * 200 + oc * 50 + tid] =
                psum[tid] + psum[64 + tid] + psum[128 + tid] + psum[192 + tid];
    }
}

extern "C" void kernel_launch(void* const* d_in, const int* in_sizes, int n_in,
                              void* d_out, int out_size, void* d_ws, size_t ws_size,
                              hipStream_t stream) {
    const float* x   = (const float*)d_in[0];
    const float* bw0 = (const float*)d_in[1];
    const float* sw0 = (const float*)d_in[2];
    const float* sc0 = (const float*)d_in[3];
    const float* bw1 = (const float*)d_in[4];
    const float* sw1 = (const float*)d_in[5];
    const float* sc1 = (const float*)d_in[6];
    const float* bw2 = (const float*)d_in[7];
    const float* sw2 = (const float*)d_in[8];
    const float* sc2 = (const float*)d_in[9];
    const float* bwc = (const float*)d_in[10];
    const float* swc = (const float*)d_in[11];
    const float* scc = (const float*)d_in[12];
    float* out = (float*)d_out;

    char* ws = (char*)d_ws;
    size_t off = 0;
    auto alloc = [&](size_t nbytes) {
        char* p = ws + off;
        off += (nbytes + 255) & ~(size_t)255;
        return p;
    };
    _Float16* W2_0 = (_Float16*)alloc(PS0 * 16);
    _Float16* W2_1 = (_Float16*)alloc(PS1 * 16);
    _Float16* W2_2 = (_Float16*)alloc(PS2 * 16);
    float* wcT = (float*)alloc(576 * 200 * 4);
    float* h2  = (float*)alloc(8 * 64 * 49 * 4);   // dedicated (atomic target)
    float* p0  = (float*)alloc((size_t)8 * 16 * 56 * 56 * 4);
    unsigned int* featP1 = (unsigned int*)alloc((size_t)8 * 32 * 14 * 14 * 16);
    unsigned int* bars = (unsigned int*)alloc(4 * 512 * sizeof(unsigned int));

    // Barrier counters/flags must be zero each replay (ws is poisoned between iters).
    hipMemsetAsync(bars, 0, 4 * 512 * sizeof(unsigned int), stream);
    fused_k<<<NBLK, 256, 0, stream>>>(
        x, bw0, sw0, sc0, bw1, sw1, sc1, bw2, sw2, sc2, bwc, swc, scc,
        W2_0, W2_1, W2_2, wcT, h2, p0, featP1, out, bars);
}

// Round 5
// 139.519 us; speedup vs baseline: 3.8271x; 1.0246x over previous
//
#include <hip/hip_runtime.h>

#define DEV __device__ __forceinline__

typedef _Float16 f16x8 __attribute__((ext_vector_type(8)));
typedef float f32x4 __attribute__((ext_vector_type(4)));
typedef unsigned int u32x4 __attribute__((ext_vector_type(4)));

// Write-through stores to the coherence point (sc0 sc1): makes inter-phase data
// agent-visible per-instruction, so grid barriers need NO wbl2/inv cache fences
// (round-3 lesson: per-block release/acquire fences = full L2 writeback+inv, ~20us/barrier).
DEV void st16_wt(void* p, u32x4 v) {
    asm volatile("global_store_dwordx4 %0, %1, off sc0 sc1" :: "v"(p), "v"(v) : "memory");
}
DEV void st4_wt(float* p, float v) {
    asm volatile("global_store_dword %0, %1, off sc0 sc1" :: "v"(p), "v"(v) : "memory");
}

// Closed-form uniform cubic B-spline (knots (j-3)*0.4-1), verified vs Cox-de Boor (R9).
// All KAN-layer inputs are >= 0, so B_0,B_1 == 0. Record: [silu, B_2..B_7, 0].
DEV f16x8 kan_feats8(float x) {
    const float sil = x / (1.0f + __expf(-x));
    const float k0 = (float)(-3) * 0.4f - 1.0f;
    const float t = (x - k0) * 2.5f;
    const float mf = floorf(t);
    const int m = (int)mf;
    const float u = t - mf, v = 1.0f - u;
    const float u2 = u * u, u3 = u2 * u;
    const float N0 = v * v * v * (1.0f / 6.0f);
    const float N1 = (3.0f * u3 - 6.0f * u2 + 4.0f) * (1.0f / 6.0f);
    const float N2 = (-3.0f * u3 + 3.0f * u2 + 3.0f * u + 1.0f) * (1.0f / 6.0f);
    const float N3 = u3 * (1.0f / 6.0f);
    f16x8 g;
    g[0] = (_Float16)sil;
#pragma unroll
    for (int jj = 0; jj < 6; ++jj) {
        const int j = jj + 2;
        float val = 0.0f;
        val = (m == j + 3) ? N0 : val;
        val = (m == j + 2) ? N1 : val;
        val = (m == j + 1) ? N2 : val;
        val = (m == j)     ? N3 : val;
        g[1 + jj] = (_Float16)val;
    }
    g[7] = (_Float16)0.0f;
    return g;
}

// Full 9-feature version (head path).
DEV void kan_feats9(float x, float* f) {
    f[0] = x / (1.0f + __expf(-x));
    const float k0 = (float)(-3) * 0.4f - 1.0f;
    const float t = (x - k0) * 2.5f;
    const float mf = floorf(t);
    const int m = (int)mf;
    const float u = t - mf, v = 1.0f - u;
    const float u2 = u * u, u3 = u2 * u;
    const float N0 = v * v * v * (1.0f / 6.0f);
    const float N1 = (3.0f * u3 - 6.0f * u2 + 4.0f) * (1.0f / 6.0f);
    const float N2 = (-3.0f * u3 + 3.0f * u2 + 3.0f * u + 1.0f) * (1.0f / 6.0f);
    const float N3 = u3 * (1.0f / 6.0f);
#pragma unroll
    for (int j = 0; j < 8; ++j) {
        float val = 0.0f;
        val = (m == j + 3) ? N0 : val;
        val = (m == j + 2) ? N1 : val;
        val = (m == j + 1) ? N2 : val;
        val = (m == j)     ? N3 : val;
        f[1 + j] = val;
    }
}

// LDS A-plane byte offsets (pitch-8 records: one 16B octet per input).
__device__ constexpr int d_l0(int ii) {   // L0: (ci,kh,kw) over 3x7x7
    const int i = ii > 146 ? 146 : ii;    // i=147 zero-weight pad slot
    const int ci = i / 49, rem = i % 49, kh = rem / 7, kw = rem % 7;
    return ((((kw & 1) * 3 + ci) * 13 + kh) * 19 + (kw >> 1)) * 16;
}
__device__ constexpr int d_l1(int i) {    // L1: (ch,kh,kw) over 16x3x3
    const int ch = i / 9, rem = i % 9, kh = rem / 3, kw = rem % 3;
    return ((((kw & 1) * 16 + ch) * 9 + kh) * 5 + (kw >> 1)) * 16;
}

// Reduced weight octet: t=0 base, t=1..6 -> sw[j=t+1]*sc, t=7 = 0. sc1 write-through.
template <int OUT_F, int IN_F>
DEV void pack_oct8(int g, const float* bw, const float* sw, const float* sc,
                   _Float16* W2) {
    const int o = g % OUT_F, i = g / OUT_F;
    f16x8 v;
    if (i < IN_F) {
        const int wi = o * IN_F + i;
        const float s = sc[wi];
        v[0] = (_Float16)bw[wi];
#pragma unroll
        for (int t = 1; t <= 6; ++t) v[t] = (_Float16)(sw[wi * 8 + t + 1] * s);
        v[7] = (_Float16)0.0f;
    } else {
#pragma unroll
        for (int t = 0; t < 8; ++t) v[t] = (_Float16)0.0f;
    }
    st16_wt(W2 + g * 8, __builtin_bit_cast(u32x4, v));
}

#define PS0 2368   // L0: 148 koct * 16
#define PS1 4608   // L1: 144 koct * 32
#define PS2 18432  // L2: 288 koct * 64
#define PS3 12800  // head
#define PS4 25088  // h2 zero
#define PSUM (PS0 + PS1 + PS2 + PS3 + PS4)

#define NBLK 784   // co-resident: LDS 27136B -> 6 blk/CU; VGPR<=128 -> >=4 blk/CU; cap >= 1024

// Manual grid barrier, fence-free (all inter-phase data is sc1 write-through).
// Round-4 lesson: a SINGLE release-flag line polled by 783 waves congests one
// TCC bank (~12us/barrier: demand ~1500 loads/us vs ~100/us line service).
// Fix: 128 flag copies 64B apart; waiter bb polls flag[bb&127] (~6 pollers/line);
// block 0 fans out the release with 128 parallel lane stores.
// Layout per phase (u32 idx): counters j*16 (j<16), flags 1024 + i*16 (i<128).
DEV void gbar(unsigned int* bars, int k) {
    asm volatile("s_waitcnt vmcnt(0)" ::: "memory");
    __syncthreads();
    unsigned int* base = bars + k * 4096;             // 16KB per phase
    if (blockIdx.x == 0) {
        if (threadIdx.x == 0) {
            __hip_atomic_fetch_add(base, 1u, __ATOMIC_RELAXED, __HIP_MEMORY_SCOPE_AGENT);
            for (;;) {
                unsigned int s = 0;
#pragma unroll
                for (int j = 0; j < 16; ++j)
                    s += __hip_atomic_load(base + j * 16, __ATOMIC_RELAXED,
                                           __HIP_MEMORY_SCOPE_AGENT);
                if (s >= (unsigned int)NBLK) break;
                __builtin_amdgcn_s_sleep(4);
            }
        }
        __syncthreads();                              // whole block waits on detection
        if (threadIdx.x < 128)                        // parallel release fan-out
            __hip_atomic_store(base + 1024 + threadIdx.x * 16, 1u,
                               __ATOMIC_RELAXED, __HIP_MEMORY_SCOPE_AGENT);
    } else {
        if (threadIdx.x == 0) {
            __hip_atomic_fetch_add(base + (blockIdx.x & 15) * 16, 1u,
                                   __ATOMIC_RELAXED, __HIP_MEMORY_SCOPE_AGENT);
            while (__hip_atomic_load(base + 1024 + (blockIdx.x & 127) * 16,
                                     __ATOMIC_RELAXED, __HIP_MEMORY_SCOPE_AGENT) == 0u)
                __builtin_amdgcn_s_sleep(2);
        }
        asm volatile("" ::: "memory");
    }
    __syncthreads();
}

// Whole network in one launch: prep | conv0 (2 tiles/blk, featurize-0 hoisted
// above barrier 0) | conv1 | conv2 (9-way K) | head, 4 grid barriers.
__global__ __launch_bounds__(256, 4) void fused_k(
    const float* __restrict__ x,
    const float* __restrict__ bw0, const float* __restrict__ sw0, const float* __restrict__ sc0,
    const float* __restrict__ bw1, const float* __restrict__ sw1, const float* __restrict__ sc1,
    const float* __restrict__ bw2, const float* __restrict__ sw2, const float* __restrict__ sc2,
    const float* __restrict__ bwc, const float* __restrict__ swc, const float* __restrict__ scc,
    _Float16* __restrict__ W2_0, _Float16* __restrict__ W2_1, _Float16* __restrict__ W2_2,
    float* __restrict__ wcT, float* __restrict__ h2,
    float* __restrict__ p0, unsigned int* __restrict__ featP1,
    float* __restrict__ out, unsigned int* __restrict__ bars) {
    __shared__ __align__(16) char smem[27136];
    const int tid = threadIdx.x;
    const int bb = blockIdx.x;

    // ---------------- phase P: weight prep + h2 zero (no LDS) ----------------
    {
        const int e = bb * 256 + tid;
        if (e < PS0) {
            pack_oct8<16, 147>(e, bw0, sw0, sc0, W2_0);
        } else if (e < PS0 + PS1) {
            pack_oct8<32, 144>(e - PS0, bw1, sw1, sc1, W2_1);
        } else if (e < PS0 + PS1 + PS2) {
            pack_oct8<64, 288>(e - PS0 - PS1, bw2, sw2, sc2, W2_2);
        } else if (e < PS0 + PS1 + PS2 + PS3) {
            const int ee = e - PS0 - PS1 - PS2;
            const int o = ee / 64, i = ee - o * 64;
            const float s = scc[ee];
            st4_wt(&wcT[(i * 9 + 0) * 200 + o], bwc[ee]);
#pragma unroll
            for (int t = 0; t < 8; ++t)
                st4_wt(&wcT[(i * 9 + 1 + t) * 200 + o], swc[ee * 8 + t] * s);
        } else if (e < PSUM) {
            st4_wt(&h2[e - PS0 - PS1 - PS2 - PS3], 0.0f);
        }
    }

    // ---------------- phase 0: conv0, 2 tiles per block ----------------
    {
        _Float16* feats = (_Float16*)smem;          // 1482*8 f16 = 23712 B
        float* pb = (float*)(smem + 23712);         // 4*8*16 f32 = 2048 B

        auto featurize = [&](int vt) {
            const int b = vt / 196;
            const int r0 = vt - b * 196;
            const int bh = r0 / 7, bw_ = r0 - (r0 / 7) * 7;
            const int ih0 = bh * 8 - 3, iw0 = bw_ * 32 - 3;
            for (int t = tid; t < 1482; t += 256) {
                const int iwh = t % 19;
                int r = t / 19;
                const int ihp = r % 13; r /= 13;
                const int ci = r % 3;
                const int par = r / 3;
                const int ih = ih0 + ihp, iw = iw0 + 2 * iwh + par;
                float xv = 0.0f;
                if (ih >= 0 && ih < 224 && iw >= 0 && iw < 224)
                    xv = x[((b * 3 + ci) * 224 + ih) * 224 + iw];
                *(f16x8*)(feats + t * 8) = kan_feats8(xv);
            }
        };

        featurize(bb);            // tile 0, weight-independent: hide barrier 0 under it
        gbar(bars, 0);            // W2_* ready; also publishes feats within block

        const int lane = tid & 63, mt = tid >> 6;
        const int l15 = lane & 15, q = lane >> 4;
        const bool q1 = q & 1, q2 = q & 2;
        const char* aBase = (const char*)feats + ((2 * mt) * 19 + l15) * 16;
        const f16x8* __restrict__ Wv = (const f16x8*)W2_0;

#pragma unroll 1
        for (int rep = 0; rep < 2; ++rep) {
            const int vt = bb + rep * NBLK;         // 0..1567, even split
            f32x4 acc = {0.f, 0.f, 0.f, 0.f};
#pragma unroll
            for (int s = 0; s < 37; ++s) {
                const int o0 = d_l0(4 * s), o1 = d_l0(4 * s + 1);
                const int o2 = d_l0(4 * s + 2), o3 = d_l0(4 * s + 3);
                const int e01 = q1 ? o1 : o0;
                const int e23 = q1 ? o3 : o2;
                const int aoff = q2 ? e23 : e01;
                const f16x8 a = *(const f16x8*)(aBase + aoff);
                const f16x8 bf = Wv[(s * 4 + q) * 16 + l15];
                acc = __builtin_amdgcn_mfma_f32_16x16x32_f16(a, bf, acc, 0, 0, 0);
            }
            pb[(mt * 8 + 2 * q + 0) * 16 + l15] = fmaxf(fmaxf(acc[0], 0.f), fmaxf(acc[1], 0.f));
            pb[(mt * 8 + 2 * q + 1) * 16 + l15] = fmaxf(fmaxf(acc[2], 0.f), fmaxf(acc[3], 0.f));
            __syncthreads();
            // pool+store tile vt; concurrently featurize next tile (disjoint LDS)
            if (rep == 0) featurize(bb + NBLK);
            {
                const int b = vt / 196;
                const int r0 = vt - b * 196;
                const int bh = r0 / 7, bw_ = r0 - (r0 / 7) * 7;
                const int pr = tid >> 7, o = (tid >> 3) & 15, wp = tid & 7;
                const float v = fmaxf(pb[((2 * pr) * 8 + wp) * 16 + o],
                                      pb[((2 * pr + 1) * 8 + wp) * 16 + o]);
                st4_wt(&p0[((b * 16 + o) * 56 + bh * 2 + pr) * 56 + bw_ * 8 + wp], v);
            }
            __syncthreads();
        }
    }
    gbar(bars, 1);

    // ---------------- phase 1: conv1 (blocks 0..391) ----------------
    if (bb < 392) {
        _Float16* feats = (_Float16*)smem;          // 1440*8 f16 = 23040 B
        float* abuf = (float*)(smem + 23040);       // 2*32*16 f32 = 4096 B
        const int b = bb / 49;
        const int r0 = bb - b * 49;
        const int bh = r0 / 7, bw = r0 - (r0 / 7) * 7;
        const int ih0 = bh * 8 - 1, iw0 = bw * 8 - 1;
        for (int t = tid; t < 1296; t += 256) {
            const int iwp = t % 9;
            int r = t / 9;
            const int ihp = r % 9;
            const int ch = r / 9;
            const int ih = ih0 + ihp, iw = iw0 + iwp;
            float xv = 0.0f;
            if (ih >= 0 && ih < 56 && iw >= 0 && iw < 56)
                xv = p0[((b * 16 + ch) * 56 + ih) * 56 + iw];
            const int slot = (((iwp & 1) * 16 + ch) * 9 + ihp) * 5 + (iwp >> 1);
            *(f16x8*)(feats + slot * 8) = kan_feats8(xv);
        }
        __syncthreads();
        const int lane = tid & 63, w = tid >> 6;
        const int kc = w >> 1, ot = w & 1;
        const int l15 = lane & 15, q = lane >> 4;
        const bool q1 = q & 1, q2 = q & 2;
        const int mh = l15 >> 2, mw = l15 & 3;
        const int ocol = ot * 16 + l15;
        const char* aBase = (const char*)feats + ((2 * mh) * 5 + mw) * 16 + kc * 5760;
        const f16x8* __restrict__ Wv = (const f16x8*)W2_1;
        f32x4 acc = {0.f, 0.f, 0.f, 0.f};
#pragma unroll
        for (int s = 0; s < 18; ++s) {
            const int o0 = d_l1(4 * s), o1 = d_l1(4 * s + 1);
            const int o2 = d_l1(4 * s + 2), o3 = d_l1(4 * s + 3);
            const int e01 = q1 ? o1 : o0;
            const int e23 = q1 ? o3 : o2;
            const int aoff = q2 ? e23 : e01;
            const f16x8 a = *(const f16x8*)(aBase + aoff);
            const f16x8 bf = Wv[(kc * 72 + s * 4 + q) * 32 + ocol];
            acc = __builtin_amdgcn_mfma_f32_16x16x32_f16(a, bf, acc, 0, 0, 0);
        }
#pragma unroll
        for (int reg = 0; reg < 4; ++reg)
            abuf[(kc * 32 + ocol) * 16 + q * 4 + reg] = acc[reg];
        __syncthreads();
        if (tid < 128) {
            const int o = tid >> 2, pp = tid & 3;
            const int hp = pp >> 1, wp = pp & 1;
            float mx = -1e30f;
#pragma unroll
            for (int dh = 0; dh < 2; ++dh)
#pragma unroll
                for (int dw = 0; dw < 2; ++dw) {
                    const int m = (2 * hp + dh) * 4 + 2 * wp + dw;
                    const float s = abuf[(0 * 32 + o) * 16 + m] + abuf[(1 * 32 + o) * 16 + m];
                    mx = fmaxf(mx, fmaxf(s, 0.0f));
                }
            const f16x8 g = kan_feats8(mx);
            const size_t idx = ((b * 32 + o) * 14 + bh * 2 + hp) * 14 + bw * 2 + wp;
            st16_wt(featP1 + idx * 4, __builtin_bit_cast(u32x4, g));
        }
    }
    gbar(bars, 2);

    // ---------------- phase 2: conv2, 9-way K-split (blocks 0..224) ----------------
    if (bb < 225) {
        unsigned int* featW = (unsigned int*)smem;   // 16*132 u32 = 8448 B
        const int c = bb % 9, rt = bb / 9;
        const int lane = tid & 63, ot = tid >> 6;
        const int q = lane >> 4, l15 = lane & 15;
        const int ocol = ot * 16 + l15;
        const u32x4 F0p = __builtin_bit_cast(u32x4, kan_feats8(0.0f));
        const int i_in = tid & 31, rbase = tid >> 5;
        int hi0[2], wi0[2], pixb[2];
        bool rv[2];
#pragma unroll
        for (int t = 0; t < 2; ++t) {
            const int n = rt * 16 + rbase + t * 8;
            const int wo_ = n % 7, ho_ = (n / 7) % 7, b_ = n / 49;
            rv[t] = (n < 392);
            hi0[t] = ho_ * 2 - 1;
            wi0[t] = wo_ * 2 - 1;
            pixb[t] = b_ * 32 * 14 * 14;
        }
        f32x4 acc = {0.f, 0.f, 0.f, 0.f};
        const f16x8* __restrict__ Wv = (const f16x8*)W2_2;
        {
            const int ii = c * 32 + i_in;
            const int ci = ii / 9, rem = ii - ci * 9;
            const int kh = rem / 3, kw = rem - kh * 3;
#pragma unroll
            for (int t = 0; t < 2; ++t) {
                const int hi = hi0[t] + kh, wi = wi0[t] + kw;
                const bool v = rv[t] && hi >= 0 && hi < 14 && wi >= 0 && wi < 14;
                u32x4 rec = F0p;
                if (v)
                    rec = *(const u32x4*)(featP1 + (size_t)(pixb[t] + (ci * 14 + hi) * 14 + wi) * 4);
                *(u32x4*)(featW + (rbase + t * 8) * 132 + i_in * 4) = rec;
            }
            __syncthreads();
            const char* arow = (const char*)featW + l15 * 528 + q * 16;
#pragma unroll
            for (int s = 0; s < 8; ++s) {
                const f16x8 a = *(const f16x8*)(arow + s * 64);
                const f16x8 bf = Wv[(c * 32 + s * 4 + q) * 64 + ocol];
                acc = __builtin_amdgcn_mfma_f32_16x16x32_f16(a, bf, acc, 0, 0, 0);
            }
        }
#pragma unroll
        for (int reg = 0; reg < 4; ++reg) {
            const int n = rt * 16 + q * 4 + reg;
            if (n < 392) {
                const int wo_ = n % 7, ho_ = (n / 7) % 7, b_ = n / 49;
                atomicAdd(h2 + ((b_ * 64 + ocol) * 7 + ho_) * 7 + wo_, acc[reg]);
            }
        }
    }
    gbar(bars, 3);

    // ---------------- phase 3: head, 32 blocks (n x 4 o-chunks, 4-way K-split) ----
    if (bb < 32) {
        float* feat = (float*)smem;                  // 576 f32
        float* psum = (float*)(smem + 2304);         // 4*64 f32
        const int n = bb >> 2, oc = bb & 3;
        if (tid < 64) {
            const float* p = h2 + (n * 64 + tid) * 49;
            float s = 0.0f;
            for (int j = 0; j < 49; ++j) {
                // h2 truth lives at the coherence point (atomics); bypass any stale L2 copy
                const float hv = __hip_atomic_load(p + j, __ATOMIC_RELAXED,
                                                   __HIP_MEMORY_SCOPE_AGENT);
                s += fmaxf(hv, 0.0f);
            }
            float f9[9];
            kan_feats9(s / 49.0f, f9);
#pragma unroll
            for (int t = 0; t < 9; ++t) feat[tid * 9 + t] = f9[t];
        }
        __syncthreads();
        const int js = tid >> 6, ol = tid & 63;
        if (ol < 50) {
            const int o = oc * 50 + ol;
            float sum = 0.0f;
            for (int j = js * 144; j < js * 144 + 144; ++j)
                sum += feat[j] * wcT[j * 200 + o];
            psum[js * 64 + ol] = sum;
        }
        __syncthreads();
        if (tid < 50)
            out[n * 200 + oc * 50 + tid] =
                psum[tid] + psum[64 + tid] + psum[128 + tid] + psum[192 + tid];
    }
}

extern "C" void kernel_launch(void* const* d_in, const int* in_sizes, int n_in,
                              void* d_out, int out_size, void* d_ws, size_t ws_size,
                              hipStream_t stream) {
    const float* x   = (const float*)d_in[0];
    const float* bw0 = (const float*)d_in[1];
    const float* sw0 = (const float*)d_in[2];
    const float* sc0 = (const float*)d_in[3];
    const float* bw1 = (const float*)d_in[4];
    const float* sw1 = (const float*)d_in[5];
    const float* sc1 = (const float*)d_in[6];
    const float* bw2 = (const float*)d_in[7];
    const float* sw2 = (const float*)d_in[8];
    const float* sc2 = (const float*)d_in[9];
    const float* bwc = (const float*)d_in[10];
    const float* swc = (const float*)d_in[11];
    const float* scc = (const float*)d_in[12];
    float* out = (float*)d_out;

    char* ws = (char*)d_ws;
    size_t off = 0;
    auto alloc = [&](size_t nbytes) {
        char* p = ws + off;
        off += (nbytes + 255) & ~(size_t)255;
        return p;
    };
    _Float16* W2_0 = (_Float16*)alloc(PS0 * 16);
    _Float16* W2_1 = (_Float16*)alloc(PS1 * 16);
    _Float16* W2_2 = (_Float16*)alloc(PS2 * 16);
    float* wcT = (float*)alloc(576 * 200 * 4);
    float* h2  = (float*)alloc(8 * 64 * 49 * 4);   // dedicated (atomic target)
    float* p0  = (float*)alloc((size_t)8 * 16 * 56 * 56 * 4);
    unsigned int* featP1 = (unsigned int*)alloc((size_t)8 * 32 * 14 * 14 * 16);
    unsigned int* bars = (unsigned int*)alloc(4 * 4096 * sizeof(unsigned int));

    // Barrier counters/flags must be zero each replay (ws is poisoned between iters).
    hipMemsetAsync(bars, 0, 4 * 4096 * sizeof(unsigned int), stream);
    fused_k<<<NBLK, 256, 0, stream>>>(
        x, bw0, sw0, sc0, bw1, sw1, sc1, bw2, sw2, sc2, bwc, swc, scc,
        W2_0, W2_1, W2_2, wcT, h2, p0, featP1, out, bars);
}

// Round 6
// 122.942 us; speedup vs baseline: 4.3431x; 1.1348x over previous
//
#include <hip/hip_runtime.h>

#define DEV __device__ __forceinline__

typedef _Float16 f16x8 __attribute__((ext_vector_type(8)));
typedef float f32x4 __attribute__((ext_vector_type(4)));
typedef unsigned int u32x4 __attribute__((ext_vector_type(4)));

// Closed-form uniform cubic B-spline (knots (j-3)*0.4-1), verified vs Cox-de Boor (R9).
// All KAN-layer inputs are >= 0, so B_0,B_1 == 0. Record: [silu, B_2..B_7, 0].
DEV f16x8 kan_feats8(float x) {
    const float sil = x / (1.0f + __expf(-x));
    const float k0 = (float)(-3) * 0.4f - 1.0f;
    const float t = (x - k0) * 2.5f;
    const float mf = floorf(t);
    const int m = (int)mf;
    const float u = t - mf, v = 1.0f - u;
    const float u2 = u * u, u3 = u2 * u;
    const float N0 = v * v * v * (1.0f / 6.0f);
    const float N1 = (3.0f * u3 - 6.0f * u2 + 4.0f) * (1.0f / 6.0f);
    const float N2 = (-3.0f * u3 + 3.0f * u2 + 3.0f * u + 1.0f) * (1.0f / 6.0f);
    const float N3 = u3 * (1.0f / 6.0f);
    f16x8 g;
    g[0] = (_Float16)sil;
#pragma unroll
    for (int jj = 0; jj < 6; ++jj) {
        const int j = jj + 2;
        float val = 0.0f;
        val = (m == j + 3) ? N0 : val;
        val = (m == j + 2) ? N1 : val;
        val = (m == j + 1) ? N2 : val;
        val = (m == j)     ? N3 : val;
        g[1 + jj] = (_Float16)val;
    }
    g[7] = (_Float16)0.0f;
    return g;
}

// Full 9-feature version (head path).
DEV void kan_feats9(float x, float* f) {
    f[0] = x / (1.0f + __expf(-x));
    const float k0 = (float)(-3) * 0.4f - 1.0f;
    const float t = (x - k0) * 2.5f;
    const float mf = floorf(t);
    const int m = (int)mf;
    const float u = t - mf, v = 1.0f - u;
    const float u2 = u * u, u3 = u2 * u;
    const float N0 = v * v * v * (1.0f / 6.0f);
    const float N1 = (3.0f * u3 - 6.0f * u2 + 4.0f) * (1.0f / 6.0f);
    const float N2 = (-3.0f * u3 + 3.0f * u2 + 3.0f * u + 1.0f) * (1.0f / 6.0f);
    const float N3 = u3 * (1.0f / 6.0f);
#pragma unroll
    for (int j = 0; j < 8; ++j) {
        float val = 0.0f;
        val = (m == j + 3) ? N0 : val;
        val = (m == j + 2) ? N1 : val;
        val = (m == j + 1) ? N2 : val;
        val = (m == j)     ? N3 : val;
        f[1 + j] = val;
    }
}

// LDS A-plane byte offsets (pitch-8 records: one 16B octet per input).
__device__ constexpr int d_l0(int ii) {   // L0: (ci,kh,kw) over 3x7x7
    const int i = ii > 146 ? 146 : ii;    // i=147 zero-weight pad slot
    const int ci = i / 49, rem = i % 49, kh = rem / 7, kw = rem % 7;
    return ((((kw & 1) * 3 + ci) * 13 + kh) * 19 + (kw >> 1)) * 16;
}
__device__ constexpr int d_l1(int i) {    // L1: (ch,kh,kw) over 16x3x3
    const int ch = i / 9, rem = i % 9, kh = rem / 3, kw = rem % 3;
    return ((((kw & 1) * 16 + ch) * 9 + kh) * 5 + (kw >> 1)) * 16;
}

// Reduced weight octet: t=0 base, t=1..6 -> sw[j=t+1]*sc, t=7 = 0.
template <int OUT_F, int IN_F>
DEV void pack_oct8(int g, const float* bw, const float* sw, const float* sc,
                   _Float16* W2) {
    const int o = g % OUT_F, i = g / OUT_F;
    f16x8 v;
    if (i < IN_F) {
        const int wi = o * IN_F + i;
        const float s = sc[wi];
        v[0] = (_Float16)bw[wi];
#pragma unroll
        for (int t = 1; t <= 6; ++t) v[t] = (_Float16)(sw[wi * 8 + t + 1] * s);
        v[7] = (_Float16)0.0f;
    } else {
#pragma unroll
        for (int t = 0; t < 8; ++t) v[t] = (_Float16)0.0f;
    }
    *(f16x8*)(W2 + g * 8) = v;
}

#define PS0 2368   // L0: 148 koct * 16
#define PS1 4608   // L1: 144 koct * 32
#define PS2 18432  // L2: 288 koct * 64
#define PS3 12800  // head
#define PS4 25088  // h2 zero
#define PSUM (PS0 + PS1 + PS2 + PS3 + PS4)

__global__ __launch_bounds__(256) void prep_k(
    const float* __restrict__ bw0, const float* __restrict__ sw0, const float* __restrict__ sc0,
    const float* __restrict__ bw1, const float* __restrict__ sw1, const float* __restrict__ sc1,
    const float* __restrict__ bw2, const float* __restrict__ sw2, const float* __restrict__ sc2,
    const float* __restrict__ bwc, const float* __restrict__ swc, const float* __restrict__ scc,
    _Float16* __restrict__ W2_0, _Float16* __restrict__ W2_1, _Float16* __restrict__ W2_2,
    float* __restrict__ wcT, float* __restrict__ h2) {
    const int e = blockIdx.x * 256 + threadIdx.x;
    if (e < PS0) {
        pack_oct8<16, 147>(e, bw0, sw0, sc0, W2_0);
    } else if (e < PS0 + PS1) {
        pack_oct8<32, 144>(e - PS0, bw1, sw1, sc1, W2_1);
    } else if (e < PS0 + PS1 + PS2) {
        pack_oct8<64, 288>(e - PS0 - PS1, bw2, sw2, sc2, W2_2);
    } else if (e < PS0 + PS1 + PS2 + PS3) {
        const int ee = e - PS0 - PS1 - PS2;
        const int o = ee / 64, i = ee - o * 64;
        const float s = scc[ee];
        wcT[(i * 9 + 0) * 200 + o] = bwc[ee];
#pragma unroll
        for (int t = 0; t < 8; ++t)
            wcT[(i * 9 + 1 + t) * 200 + o] = swc[ee * 8 + t] * s;
    } else if (e < PSUM) {
        h2[e - PS0 - PS1 - PS2 - PS3] = 0.0f;
    }
}

// L0: featurize-in-block (pitch-8) + 37 MFMA steps + fused relu/2x2 pool -> raw p0.
// LDS 25760 B; request 5 blocks/CU for TLP.
__global__ __launch_bounds__(256, 5) void conv0_k(
    const float* __restrict__ x, const _Float16* __restrict__ W2,
    float* __restrict__ p0) {
    __shared__ __align__(16) _Float16 feats[1482 * 8];
    __shared__ float pb[4 * 8 * 16];
    const int tid = threadIdx.x;
    const int vt = blockIdx.x;
    const int b = vt / 196;
    const int r0 = vt - b * 196;
    const int bh = r0 / 7, bw = r0 - (r0 / 7) * 7;
    const int ih0 = bh * 8 - 3, iw0 = bw * 32 - 3;
    for (int t = tid; t < 1482; t += 256) {
        const int iwh = t % 19;
        int r = t / 19;
        const int ihp = r % 13; r /= 13;
        const int ci = r % 3;
        const int par = r / 3;
        const int ih = ih0 + ihp, iw = iw0 + 2 * iwh + par;
        float xv = 0.0f;
        if (ih >= 0 && ih < 224 && iw >= 0 && iw < 224)
            xv = x[((b * 3 + ci) * 224 + ih) * 224 + iw];
        *(f16x8*)(feats + t * 8) = kan_feats8(xv);
    }
    __syncthreads();
    const int lane = tid & 63, mt = tid >> 6;
    const int l15 = lane & 15, q = lane >> 4;
    const bool q1 = q & 1, q2 = q & 2;
    const char* aBase = (const char*)feats + ((2 * mt) * 19 + l15) * 16;
    const f16x8* __restrict__ Wv = (const f16x8*)W2;
    f32x4 acc = {0.f, 0.f, 0.f, 0.f};
#pragma unroll
    for (int s = 0; s < 37; ++s) {
        const int o0 = d_l0(4 * s), o1 = d_l0(4 * s + 1);
        const int o2 = d_l0(4 * s + 2), o3 = d_l0(4 * s + 3);
        const int e01 = q1 ? o1 : o0;
        const int e23 = q1 ? o3 : o2;
        const int aoff = q2 ? e23 : e01;
        const f16x8 a = *(const f16x8*)(aBase + aoff);
        const f16x8 bf = Wv[(s * 4 + q) * 16 + l15];
        acc = __builtin_amdgcn_mfma_f32_16x16x32_f16(a, bf, acc, 0, 0, 0);
    }
    pb[(mt * 8 + 2 * q + 0) * 16 + l15] = fmaxf(fmaxf(acc[0], 0.f), fmaxf(acc[1], 0.f));
    pb[(mt * 8 + 2 * q + 1) * 16 + l15] = fmaxf(fmaxf(acc[2], 0.f), fmaxf(acc[3], 0.f));
    __syncthreads();
    const int pr = tid >> 7, o = (tid >> 3) & 15, wp = tid & 7;
    const float v = fmaxf(pb[((2 * pr) * 8 + wp) * 16 + o],
                          pb[((2 * pr + 1) * 8 + wp) * 16 + o]);
    p0[((b * 16 + o) * 56 + bh * 2 + pr) * 56 + bw * 8 + wp] = v;
}

// L1: featurize-in-block + 36 MFMA steps (wave-pairs split K, LDS reduce) +
// fused relu/pool/featurize -> featP1 (16B records). LDS 27136 B; 5 blocks/CU.
__global__ __launch_bounds__(256, 5) void conv1_k(
    const float* __restrict__ p0, const _Float16* __restrict__ W2,
    unsigned int* __restrict__ featP1) {
    __shared__ __align__(16) _Float16 feats[1440 * 8];
    __shared__ float abuf[2 * 32 * 16];
    const int tid = threadIdx.x;
    const int vt = blockIdx.x;
    const int b = vt / 49;
    const int r0 = vt - b * 49;
    const int bh = r0 / 7, bw = r0 - (r0 / 7) * 7;
    const int ih0 = bh * 8 - 1, iw0 = bw * 8 - 1;
    for (int t = tid; t < 1296; t += 256) {
        const int iwp = t % 9;
        int r = t / 9;
        const int ihp = r % 9;
        const int ch = r / 9;
        const int ih = ih0 + ihp, iw = iw0 + iwp;
        float xv = 0.0f;
        if (ih >= 0 && ih < 56 && iw >= 0 && iw < 56)
            xv = p0[((b * 16 + ch) * 56 + ih) * 56 + iw];
        const int slot = (((iwp & 1) * 16 + ch) * 9 + ihp) * 5 + (iwp >> 1);
        *(f16x8*)(feats + slot * 8) = kan_feats8(xv);
    }
    __syncthreads();
    const int lane = tid & 63, w = tid >> 6;
    const int kc = w >> 1, ot = w & 1;
    const int l15 = lane & 15, q = lane >> 4;
    const bool q1 = q & 1, q2 = q & 2;
    const int mh = l15 >> 2, mw = l15 & 3;
    const int ocol = ot * 16 + l15;
    const char* aBase = (const char*)feats + ((2 * mh) * 5 + mw) * 16 + kc * 5760;
    const f16x8* __restrict__ Wv = (const f16x8*)W2;
    f32x4 acc = {0.f, 0.f, 0.f, 0.f};
#pragma unroll
    for (int s = 0; s < 18; ++s) {
        const int o0 = d_l1(4 * s), o1 = d_l1(4 * s + 1);
        const int o2 = d_l1(4 * s + 2), o3 = d_l1(4 * s + 3);
        const int e01 = q1 ? o1 : o0;
        const int e23 = q1 ? o3 : o2;
        const int aoff = q2 ? e23 : e01;
        const f16x8 a = *(const f16x8*)(aBase + aoff);
        const f16x8 bf = Wv[(kc * 72 + s * 4 + q) * 32 + ocol];
        acc = __builtin_amdgcn_mfma_f32_16x16x32_f16(a, bf, acc, 0, 0, 0);
    }
#pragma unroll
    for (int reg = 0; reg < 4; ++reg)
        abuf[(kc * 32 + ocol) * 16 + q * 4 + reg] = acc[reg];
    __syncthreads();
    if (tid < 128) {
        const int o = tid >> 2, pp = tid & 3;
        const int hp = pp >> 1, wp = pp & 1;
        float mx = -1e30f;
#pragma unroll
        for (int dh = 0; dh < 2; ++dh)
#pragma unroll
            for (int dw = 0; dw < 2; ++dw) {
                const int m = (2 * hp + dh) * 4 + 2 * wp + dw;
                const float s = abuf[(0 * 32 + o) * 16 + m] + abuf[(1 * 32 + o) * 16 + m];
                mx = fmaxf(mx, fmaxf(s, 0.0f));
            }
        const f16x8 g = kan_feats8(mx);
        const size_t idx = ((b * 32 + o) * 14 + bh * 2 + hp) * 14 + bw * 2 + wp;
        *(u32x4*)(featP1 + idx * 4) = __builtin_bit_cast(u32x4, g);
    }
}

// L2: gather 16B records + 8 MFMA steps per block, 9-way K-split (225 blocks,
// single gather round, atomicAdd h2). Improved vs R0's 75-block/3-round version
// (verified in fused rounds 3-5). LDS 8448 B.
__global__ __launch_bounds__(256, 4) void conv2_k(
    const unsigned int* __restrict__ fm, const _Float16* __restrict__ W2,
    float* __restrict__ h2) {
    __shared__ __align__(16) unsigned int featW[16 * 132];
    const int tid = threadIdx.x;
    const int c = blockIdx.x % 9, rt = blockIdx.x / 9;
    const int lane = tid & 63, ot = tid >> 6;
    const int q = lane >> 4, l15 = lane & 15;
    const int ocol = ot * 16 + l15;
    const u32x4 F0p = __builtin_bit_cast(u32x4, kan_feats8(0.0f));
    const int i_in = tid & 31, rbase = tid >> 5;
    int hi0[2], wi0[2], pixb[2];
    bool rv[2];
#pragma unroll
    for (int t = 0; t < 2; ++t) {
        const int n = rt * 16 + rbase + t * 8;
        const int wo_ = n % 7, ho_ = (n / 7) % 7, b_ = n / 49;
        rv[t] = (n < 392);
        hi0[t] = ho_ * 2 - 1;
        wi0[t] = wo_ * 2 - 1;
        pixb[t] = b_ * 32 * 14 * 14;
    }
    f32x4 acc = {0.f, 0.f, 0.f, 0.f};
    const f16x8* __restrict__ Wv = (const f16x8*)W2;
    {
        const int ii = c * 32 + i_in;
        const int ci = ii / 9, rem = ii - ci * 9;
        const int kh = rem / 3, kw = rem - kh * 3;
#pragma unroll
        for (int t = 0; t < 2; ++t) {
            const int hi = hi0[t] + kh, wi = wi0[t] + kw;
            const bool v = rv[t] && hi >= 0 && hi < 14 && wi >= 0 && wi < 14;
            u32x4 rec = F0p;
            if (v)
                rec = *(const u32x4*)(fm + (size_t)(pixb[t] + (ci * 14 + hi) * 14 + wi) * 4);
            *(u32x4*)(featW + (rbase + t * 8) * 132 + i_in * 4) = rec;
        }
        __syncthreads();
        const char* arow = (const char*)featW + l15 * 528 + q * 16;
#pragma unroll
        for (int s = 0; s < 8; ++s) {
            const f16x8 a = *(const f16x8*)(arow + s * 64);
            const f16x8 bf = Wv[(c * 32 + s * 4 + q) * 64 + ocol];
            acc = __builtin_amdgcn_mfma_f32_16x16x32_f16(a, bf, acc, 0, 0, 0);
        }
    }
#pragma unroll
    for (int reg = 0; reg < 4; ++reg) {
        const int n = rt * 16 + q * 4 + reg;
        if (n < 392) {
            const int wo_ = n % 7, ho_ = (n / 7) % 7, b_ = n / 49;
            atomicAdd(h2 + ((b_ * 64 + ocol) * 7 + ho_) * 7 + wo_, acc[reg]);
        }
    }
}

// relu + global-avg-pool + fp32 classifier. 32 blocks (n x 4 o-chunks, 4-way
// K-split) — improved vs R0's 8-block version (verified in fused rounds 3-5).
__global__ __launch_bounds__(256) void head_k(
    const float* __restrict__ h2, const float* __restrict__ wT,
    float* __restrict__ out) {
    __shared__ float feat[576];
    __shared__ float psum[4 * 64];
    const int tid = threadIdx.x;
    const int n = blockIdx.x >> 2, oc = blockIdx.x & 3;
    if (tid < 64) {
        const float* p = h2 + (n * 64 + tid) * 49;
        float s = 0.0f;
        for (int j = 0; j < 49; ++j) s += fmaxf(p[j], 0.0f);
        float f9[9];
        kan_feats9(s / 49.0f, f9);
#pragma unroll
        for (int t = 0; t < 9; ++t) feat[tid * 9 + t] = f9[t];
    }
    __syncthreads();
    const int js = tid >> 6, ol = tid & 63;
    if (ol < 50) {
        const int o = oc * 50 + ol;
        float sum = 0.0f;
        for (int j = js * 144; j < js * 144 + 144; ++j)
            sum += feat[j] * wT[j * 200 + o];
        psum[js * 64 + ol] = sum;
    }
    __syncthreads();
    if (tid < 50)
        out[n * 200 + oc * 50 + tid] =
            psum[tid] + psum[64 + tid] + psum[128 + tid] + psum[192 + tid];
}

extern "C" void kernel_launch(void* const* d_in, const int* in_sizes, int n_in,
                              void* d_out, int out_size, void* d_ws, size_t ws_size,
                              hipStream_t stream) {
    const float* x   = (const float*)d_in[0];
    const float* bw0 = (const float*)d_in[1];
    const float* sw0 = (const float*)d_in[2];
    const float* sc0 = (const float*)d_in[3];
    const float* bw1 = (const float*)d_in[4];
    const float* sw1 = (const float*)d_in[5];
    const float* sc1 = (const float*)d_in[6];
    const float* bw2 = (const float*)d_in[7];
    const float* sw2 = (const float*)d_in[8];
    const float* sc2 = (const float*)d_in[9];
    const float* bwc = (const float*)d_in[10];
    const float* swc = (const float*)d_in[11];
    const float* scc = (const float*)d_in[12];
    float* out = (float*)d_out;

    char* ws = (char*)d_ws;
    size_t off = 0;
    auto alloc = [&](size_t nbytes) {
        char* p = ws + off;
        off += (nbytes + 255) & ~(size_t)255;
        return p;
    };
    _Float16* W2_0 = (_Float16*)alloc(PS0 * 16);
    _Float16* W2_1 = (_Float16*)alloc(PS1 * 16);
    _Float16* W2_2 = (_Float16*)alloc(PS2 * 16);
    float* wcT = (float*)alloc(576 * 200 * 4);
    float* h2  = (float*)alloc(8 * 64 * 49 * 4);   // dedicated (atomic target)
    float* p0  = (float*)alloc((size_t)8 * 16 * 56 * 56 * 4);
    unsigned int* featP1 = (unsigned int*)alloc((size_t)8 * 32 * 14 * 14 * 16);

    prep_k<<<(PSUM + 255) / 256, 256, 0, stream>>>(
        bw0, sw0, sc0, bw1, sw1, sc1, bw2, sw2, sc2, bwc, swc, scc,
        W2_0, W2_1, W2_2, wcT, h2);
    conv0_k<<<1568, 256, 0, stream>>>(x, W2_0, p0);
    conv1_k<<<392, 256, 0, stream>>>(p0, W2_1, featP1);
    conv2_k<<<225, 256, 0, stream>>>(featP1, W2_2, h2);
    head_k<<<32, 256, 0, stream>>>(h2, wcT, out);
}